// Round 1
// baseline (2194.852 us; speedup 1.0000x reference)
//
#include <hip/hip_runtime.h>
#include <math.h>

#define RDIM 8192   // B*S
#define DDIM 1024   // 2*L
#define NDIM 8192
#define LDIM 512
#define BM 64
#define BN 64
#define BK 16
#define NTILES (NDIM / BN)   // 128

#define OFF_REAL 0
#define OFF_IMAG 4194304
#define OFF_SAL  8388608
#define OFF_CONF 8396800
#define OFF_LOSS 8404992
#define OFF_IDX  8404993

// ---------------- norms: znorm[row] = sum(z^2), cnorm[n] = sum(c^2) ----------------
__global__ __launch_bounds__(256)
void norms_kernel(const float* __restrict__ gw_real, const float* __restrict__ gw_imag,
                  const float* __restrict__ codebook,
                  float* __restrict__ znorm, float* __restrict__ cnorm) {
  const int id = blockIdx.x;   // [0, RDIM+NDIM)
  const int t = threadIdx.x;   // 256
  float s;
  if (id < RDIM) {
    const float4* zr = reinterpret_cast<const float4*>(gw_real + (size_t)id * LDIM);
    const float4* zi = reinterpret_cast<const float4*>(gw_imag + (size_t)id * LDIM);
    const float4 v = (t < 128) ? zr[t] : zi[t - 128];
    s = v.x*v.x + v.y*v.y + v.z*v.z + v.w*v.w;
  } else {
    const float4* c = reinterpret_cast<const float4*>(codebook + (size_t)(id - RDIM) * DDIM);
    const float4 v = c[t];
    s = v.x*v.x + v.y*v.y + v.z*v.z + v.w*v.w;
  }
  __shared__ float red[256];
  red[t] = s;
  __syncthreads();
  for (int st = 128; st > 0; st >>= 1) {
    if (t < st) red[t] += red[t + st];
    __syncthreads();
  }
  if (t == 0) {
    if (id < RDIM) znorm[id] = red[0];
    else           cnorm[id - RDIM] = red[0];
  }
}

// ---------------- fused distance GEMM + per-tile argmin ----------------
// 64x64 output tile per block, 256 threads, 4x4 per thread, BK=16 staged in LDS.
__global__ __launch_bounds__(256)
void dist_kernel(const float* __restrict__ gw_real, const float* __restrict__ gw_imag,
                 const float* __restrict__ codebook, const int* __restrict__ prev,
                 const float* __restrict__ adj, const float* __restrict__ znorm,
                 const float* __restrict__ cnorm,
                 float* __restrict__ ws_min, int* __restrict__ ws_idx) {
  __shared__ float As[BK][BM];
  __shared__ float Bs[BK][BN];
  __shared__ int prevs[BM];
  const int bm = blockIdx.x, bn = blockIdx.y;
  const int row0 = bm * BM, col0 = bn * BN;
  const int tid = threadIdx.x;
  const int tx = tid & 15, ty = tid >> 4;
  if (tid < BM) prevs[tid] = prev[row0 + tid];
  const int lm = tid >> 2;          // 0..63 : which row of the tile this thread stages
  const int lk = (tid & 3) << 2;    // 0,4,8,12 : k sub-offset (float4)
  const int arow = row0 + lm;
  const int brow = col0 + lm;
  float acc[4][4] = {{0.f, 0.f, 0.f, 0.f}, {0.f, 0.f, 0.f, 0.f},
                     {0.f, 0.f, 0.f, 0.f}, {0.f, 0.f, 0.f, 0.f}};
  for (int kk = 0; kk < DDIM; kk += BK) {
    const int k = kk + lk;
    float4 a, b;
    if (k < LDIM) a = *reinterpret_cast<const float4*>(gw_real + (size_t)arow * LDIM + k);
    else          a = *reinterpret_cast<const float4*>(gw_imag + (size_t)arow * LDIM + (k - LDIM));
    b = *reinterpret_cast<const float4*>(codebook + (size_t)brow * DDIM + k);
    __syncthreads();
    As[lk + 0][lm] = a.x; As[lk + 1][lm] = a.y; As[lk + 2][lm] = a.z; As[lk + 3][lm] = a.w;
    Bs[lk + 0][lm] = b.x; Bs[lk + 1][lm] = b.y; Bs[lk + 2][lm] = b.z; Bs[lk + 3][lm] = b.w;
    __syncthreads();
#pragma unroll
    for (int k2 = 0; k2 < BK; ++k2) {
      const float4 a4 = *reinterpret_cast<const float4*>(&As[k2][ty << 2]);
      const float4 b4 = *reinterpret_cast<const float4*>(&Bs[k2][tx << 2]);
      const float av[4] = {a4.x, a4.y, a4.z, a4.w};
      const float bv[4] = {b4.x, b4.y, b4.z, b4.w};
#pragma unroll
      for (int i = 0; i < 4; ++i)
#pragma unroll
        for (int j = 0; j < 4; ++j)
          acc[i][j] = fmaf(av[i], bv[j], acc[i][j]);
    }
  }
  // epilogue: d = (znorm + cnorm) - 2*dot - 0.8*sigmoid(adj[prev, col]); per-row tile argmin
  const float4 cn4 = *reinterpret_cast<const float4*>(cnorm + col0 + (tx << 2));
  const float cnv[4] = {cn4.x, cn4.y, cn4.z, cn4.w};
#pragma unroll
  for (int i = 0; i < 4; ++i) {
    const int rsub = (ty << 2) + i;
    const int row = row0 + rsub;
    const float zn = znorm[row];
    const int p = prevs[rsub];
    const float4 ad4 = *reinterpret_cast<const float4*>(adj + (size_t)p * NDIM + col0 + (tx << 2));
    const float adv[4] = {ad4.x, ad4.y, ad4.z, ad4.w};
    float bv = 3.4e38f;
    int bi = -1;
#pragma unroll
    for (int j = 0; j < 4; ++j) {
      const float bias = 0.8f * (1.0f / (1.0f + expf(-adv[j])));
      const float dv = (zn + cnv[j]) - 2.0f * acc[i][j] - bias;
      const int col = col0 + (tx << 2) + j;
      if (dv < bv) { bv = dv; bi = col; }   // strict < keeps lowest index on ties
    }
    // reduce across the 16 tx lanes (same wave, lane groups of 16)
    for (int m = 1; m < 16; m <<= 1) {
      const float ov = __shfl_xor(bv, m, 64);
      const int   oi = __shfl_xor(bi, m, 64);
      if (ov < bv || (ov == bv && oi < bi)) { bv = ov; bi = oi; }
    }
    if (tx == 0) {
      ws_min[(size_t)row * NTILES + bn] = bv;
      ws_idx[(size_t)row * NTILES + bn] = bi;
    }
  }
}

// ---------------- final argmin over the 128 column tiles ----------------
__global__ __launch_bounds__(128)
void argmin_reduce(const float* __restrict__ ws_min, const int* __restrict__ ws_idx,
                   float* __restrict__ out, float* __restrict__ minfinal,
                   int* __restrict__ idxfinal) {
  const int row = blockIdx.x;
  const int t = threadIdx.x;  // 128
  __shared__ float sv[128];
  __shared__ int   si[128];
  sv[t] = ws_min[(size_t)row * NTILES + t];
  si[t] = ws_idx[(size_t)row * NTILES + t];
  __syncthreads();
  for (int s = 64; s > 0; s >>= 1) {
    if (t < s) {
      const float ov = sv[t + s];
      const int   oi = si[t + s];
      if (ov < sv[t] || (ov == sv[t] && oi < si[t])) { sv[t] = ov; si[t] = oi; }
    }
    __syncthreads();
  }
  if (t == 0) {
    out[OFF_IDX + row] = (float)si[0];
    minfinal[row] = sv[0];
    idxfinal[row] = si[0];
  }
}

// ---------------- epilogue: proposals, salience, confidence, per-row vq loss ----------------
__global__ __launch_bounds__(256)
void epilogue_kernel(const float* __restrict__ gw_real, const float* __restrict__ gw_imag,
                     const float* __restrict__ codebook,
                     const float* __restrict__ sal_w, const float* __restrict__ sal_b,
                     const float* __restrict__ conf_w, const float* __restrict__ conf_b,
                     const float* __restrict__ minfinal, const int* __restrict__ idxfinal,
                     float* __restrict__ out, float* __restrict__ rowloss) {
  const int row = blockIdx.x;
  const int t = threadIdx.x;   // 256, one float4 (4 of D=1024) each
  const int k = t << 2;
  const int idx = idxfinal[row];
  const float4 q = *reinterpret_cast<const float4*>(codebook + (size_t)idx * DDIM + k);
  float4 z;
  if (k < LDIM) z = *reinterpret_cast<const float4*>(gw_real + (size_t)row * LDIM + k);
  else          z = *reinterpret_cast<const float4*>(gw_imag + (size_t)row * LDIM + (k - LDIM));
  // z_q_st = z + (z_q - z), matching reference fp32 op order
  const float dx = q.x - z.x, dy = q.y - z.y, dz = q.z - z.z, dw = q.w - z.w;
  float4 st;
  st.x = z.x + dx; st.y = z.y + dy; st.z = z.z + dz; st.w = z.w + dw;
  float* dst = (k < LDIM) ? (out + OFF_REAL + (size_t)row * LDIM + k)
                          : (out + OFF_IMAG + (size_t)row * LDIM + (k - LDIM));
  *reinterpret_cast<float4*>(dst) = st;
  const float4 sw = *reinterpret_cast<const float4*>(sal_w + k);
  const float4 cw = *reinterpret_cast<const float4*>(conf_w + k);
  const float sdot = st.x*sw.x + st.y*sw.y + st.z*sw.z + st.w*sw.w;
  const float cdot = st.x*cw.x + st.y*cw.y + st.z*cw.z + st.w*cw.w;
  const float dif = dx*dx + dy*dy + dz*dz + dw*dw;
  __shared__ float r1[256], r2[256], r3[256];
  r1[t] = sdot; r2[t] = cdot; r3[t] = dif;
  __syncthreads();
  for (int s = 128; s > 0; s >>= 1) {
    if (t < s) { r1[t] += r1[t + s]; r2[t] += r2[t + s]; r3[t] += r3[t + s]; }
    __syncthreads();
  }
  if (t == 0) {
    out[OFF_SAL + row]  = r1[0] + sal_b[0] + 0.1f * (-minfinal[row]);
    out[OFF_CONF + row] = 1.0f / (1.0f + expf(-(r2[0] + conf_b[0])));
    rowloss[row] = r3[0];
  }
}

// ---------------- deterministic final loss reduce ----------------
__global__ __launch_bounds__(256)
void loss_kernel(const float* __restrict__ rowloss, float* __restrict__ out) {
  const int t = threadIdx.x;
  float s = 0.f;
  for (int i = t; i < RDIM; i += 256) s += rowloss[i];
  __shared__ float red[256];
  red[t] = s;
  __syncthreads();
  for (int st = 128; st > 0; st >>= 1) {
    if (t < st) red[t] += red[t + st];
    __syncthreads();
  }
  if (t == 0) {
    const float m = red[0] / (float)((size_t)RDIM * DDIM);   // loss_vq == loss_commit numerically
    out[OFF_LOSS] = m + 0.01f * m;
  }
}

extern "C" void kernel_launch(void* const* d_in, const int* in_sizes, int n_in,
                              void* d_out, int out_size, void* d_ws, size_t ws_size,
                              hipStream_t stream) {
  const float* gw_real  = (const float*)d_in[0];
  const float* gw_imag  = (const float*)d_in[1];
  const int*   prev     = (const int*)d_in[2];
  const float* codebook = (const float*)d_in[3];
  const float* adj      = (const float*)d_in[4];
  const float* sal_w    = (const float*)d_in[5];
  const float* sal_b    = (const float*)d_in[6];
  const float* conf_w   = (const float*)d_in[7];
  const float* conf_b   = (const float*)d_in[8];
  float* out = (float*)d_out;

  char* ws = (char*)d_ws;
  float* ws_min   = (float*)ws;                                   // 8192*128 f32 = 4 MB
  int*   ws_idx   = (int*)(ws + (size_t)RDIM * NTILES * 4);       // 4 MB
  float* znorm    = (float*)(ws + (size_t)RDIM * NTILES * 8);     // 32 KB
  float* cnorm    = znorm + RDIM;                                 // 32 KB
  float* minfinal = cnorm + NDIM;                                 // 32 KB
  int*   idxfinal = (int*)(minfinal + RDIM);                      // 32 KB
  float* rowloss  = (float*)(idxfinal + RDIM);                    // 32 KB

  norms_kernel<<<RDIM + NDIM, 256, 0, stream>>>(gw_real, gw_imag, codebook, znorm, cnorm);
  dist_kernel<<<dim3(RDIM / BM, NDIM / BN), 256, 0, stream>>>(
      gw_real, gw_imag, codebook, prev, adj, znorm, cnorm, ws_min, ws_idx);
  argmin_reduce<<<RDIM, 128, 0, stream>>>(ws_min, ws_idx, out, minfinal, idxfinal);
  epilogue_kernel<<<RDIM, 256, 0, stream>>>(gw_real, gw_imag, codebook, sal_w, sal_b,
                                            conf_w, conf_b, minfinal, idxfinal, out, rowloss);
  loss_kernel<<<1, 256, 0, stream>>>(rowloss, out);
}

// Round 2
// 910.201 us; speedup vs baseline: 2.4114x; 2.4114x over previous
//
#include <hip/hip_runtime.h>
#include <math.h>

#define RDIM 8192   // B*S
#define DDIM 1024   // 2*L
#define NDIM 8192
#define LDIM 512

#define OFF_REAL 0
#define OFF_IMAG 4194304
#define OFF_SAL  8388608
#define OFF_CONF 8396800
#define OFF_LOSS 8404992
#define OFF_IDX  8404993

#define EPS_REFINE 0.02f
#define FLT_BIG 3.4e38f

typedef __attribute__((ext_vector_type(8))) short bf16x8;
typedef __attribute__((ext_vector_type(4))) float f32x4;

__device__ __forceinline__ unsigned short f2bf(float x) {
  unsigned u = __builtin_bit_cast(unsigned, x);
  unsigned r = (u + 0x7fff + ((u >> 16) & 1)) >> 16;
  return (unsigned short)r;
}
__device__ __forceinline__ float bf2f(unsigned short h) {
  unsigned u = ((unsigned)h) << 16;
  return __builtin_bit_cast(float, u);
}

__device__ __forceinline__ void load_lds16(const void* g, void* l) {
  __builtin_amdgcn_global_load_lds((const __attribute__((address_space(1))) void*)g,
                                   (__attribute__((address_space(3))) void*)l, 16, 0, 0);
}

// lexicographic top-2 helpers (value, then lower index wins ties)
__device__ __forceinline__ void top2_ins(float& v1, int& i1, float& v2, int& i2,
                                         float d, int c) {
  if (d < v1 || (d == v1 && c < i1)) { v2 = v1; i2 = i1; v1 = d; i1 = c; }
  else if (d < v2 || (d == v2 && c < i2)) { v2 = d; i2 = c; }
}
__device__ __forceinline__ void top2_merge(float& v1, int& i1, float& v2, int& i2,
                                           float o1, int oi1, float o2, int oi2) {
  if (o1 < v1 || (o1 == v1 && oi1 < i1)) {
    float t = v1; int ti = i1;
    v1 = o1; i1 = oi1;
    if (o2 < t || (o2 == t && oi2 < ti)) { v2 = o2; i2 = oi2; }
    else { v2 = t; i2 = ti; }
  } else {
    if (o1 < v2 || (o1 == v2 && oi1 < i2)) { v2 = o1; i2 = oi1; }
  }
}

// ============ NEW PATH ============

// norms + bf16 hi/lo split of z (concat real,imag) and codebook
__global__ __launch_bounds__(256)
void split_norms_kernel(const float* __restrict__ gw_real, const float* __restrict__ gw_imag,
                        const float* __restrict__ codebook,
                        unsigned short* __restrict__ zhi, unsigned short* __restrict__ zlo,
                        unsigned short* __restrict__ chi, unsigned short* __restrict__ clo,
                        float* __restrict__ znorm, float* __restrict__ cnorm) {
  const int id = blockIdx.x;   // [0, 16384)
  const int t = threadIdx.x;   // 256
  float4 v;
  unsigned short *hi, *lo;
  size_t off;
  if (id < RDIM) {
    v = (t < 128) ? reinterpret_cast<const float4*>(gw_real + (size_t)id * LDIM)[t]
                  : reinterpret_cast<const float4*>(gw_imag + (size_t)id * LDIM)[t - 128];
    off = (size_t)id * DDIM + t * 4; hi = zhi; lo = zlo;
  } else {
    const int n = id - RDIM;
    v = reinterpret_cast<const float4*>(codebook + (size_t)n * DDIM)[t];
    off = (size_t)n * DDIM + t * 4; hi = chi; lo = clo;
  }
  const float f[4] = {v.x, v.y, v.z, v.w};
  unsigned short hs[4], ls[4];
#pragma unroll
  for (int i = 0; i < 4; ++i) {
    hs[i] = f2bf(f[i]);
    ls[i] = f2bf(f[i] - bf2f(hs[i]));
  }
  *reinterpret_cast<ushort4*>(hi + off) = make_ushort4(hs[0], hs[1], hs[2], hs[3]);
  *reinterpret_cast<ushort4*>(lo + off) = make_ushort4(ls[0], ls[1], ls[2], ls[3]);
  float s = v.x*v.x + v.y*v.y + v.z*v.z + v.w*v.w;
  __shared__ float red[256];
  red[t] = s;
  __syncthreads();
  for (int st = 128; st > 0; st >>= 1) {
    if (t < st) red[t] += red[t + st];
    __syncthreads();
  }
  if (t == 0) {
    if (id < RDIM) znorm[id] = red[0];
    else           cnorm[id - RDIM] = red[0];
  }
}

// 128x128 tile MFMA distance kernel, split-bf16 (hi*hi + hi*lo + lo*hi), top-2 per tile
__global__ __launch_bounds__(256)
void dist_mfma_kernel(const unsigned short* __restrict__ zhi, const unsigned short* __restrict__ zlo,
                      const unsigned short* __restrict__ chi, const unsigned short* __restrict__ clo,
                      const int* __restrict__ prev, const float* __restrict__ adj,
                      const float* __restrict__ znorm, const float* __restrict__ cnorm,
                      float* __restrict__ wsv1, int* __restrict__ wsi1,
                      float* __restrict__ wsv2, int* __restrict__ wsi2) {
  __shared__ unsigned short tiles[4][4096];   // zhi, zlo, chi, clo : [128][32] swizzled
  __shared__ float sv1[2][128], sv2[2][128];
  __shared__ int   si1[2][128], si2[2][128];

  const int bm = blockIdx.x, bn = blockIdx.y;
  const int row0 = bm * 128, col0 = bn * 128;
  const int tid = threadIdx.x;
  const int w = tid >> 6, l = tid & 63;
  const int wr = w >> 1, wc = w & 1;
  const int lr = l & 15, lg = l >> 4;

  // staging constants: physical chunk -> pre-swizzled global source (rule #21)
  const int idx0 = w * 128 + l;
  const int idx1 = idx0 + 64;
  const int r0_ = idx0 >> 2, r1_ = idx1 >> 2;
  const int lc0 = (idx0 & 3) ^ ((r0_ >> 1) & 3);
  const int lc1 = (idx1 & 3) ^ ((r1_ >> 1) & 3);
  const size_t zo0 = (size_t)(row0 + r0_) * DDIM + lc0 * 8;
  const size_t zo1 = (size_t)(row0 + r1_) * DDIM + lc1 * 8;
  const size_t co0 = (size_t)(col0 + r0_) * DDIM + lc0 * 8;
  const size_t co1 = (size_t)(col0 + r1_) * DDIM + lc1 * 8;
  unsigned short* const lds0 = &tiles[0][w * 1024];

  const int swz = (lr >> 1) & 3;
  const int cpa = lg ^ swz;
  const int fragoff = lr * 32 + cpa * 8;   // + row_block*16*32

  f32x4 acc[4][4];
#pragma unroll
  for (int m = 0; m < 4; ++m)
#pragma unroll
    for (int n = 0; n < 4; ++n)
      acc[m][n] = (f32x4){0.f, 0.f, 0.f, 0.f};

  for (int kk = 0; kk < DDIM; kk += 32) {
    __syncthreads();
    load_lds16(zhi + zo0 + kk, lds0);
    load_lds16(zhi + zo1 + kk, lds0 + 512);
    load_lds16(zlo + zo0 + kk, lds0 + 4096);
    load_lds16(zlo + zo1 + kk, lds0 + 4096 + 512);
    load_lds16(chi + co0 + kk, lds0 + 8192);
    load_lds16(chi + co1 + kk, lds0 + 8192 + 512);
    load_lds16(clo + co0 + kk, lds0 + 12288);
    load_lds16(clo + co1 + kk, lds0 + 12288 + 512);
    __syncthreads();

    bf16x8 bh[4], bl[4];
#pragma unroll
    for (int n = 0; n < 4; ++n) {
      const int off = (wc * 64 + n * 16) * 32 + fragoff;
      bh[n] = *reinterpret_cast<const bf16x8*>(&tiles[2][off]);
      bl[n] = *reinterpret_cast<const bf16x8*>(&tiles[3][off]);
    }
#pragma unroll
    for (int m = 0; m < 4; ++m) {
      const int off = (wr * 64 + m * 16) * 32 + fragoff;
      const bf16x8 ah = *reinterpret_cast<const bf16x8*>(&tiles[0][off]);
      const bf16x8 al = *reinterpret_cast<const bf16x8*>(&tiles[1][off]);
#pragma unroll
      for (int n = 0; n < 4; ++n) {
        acc[m][n] = __builtin_amdgcn_mfma_f32_16x16x32_bf16(ah, bh[n], acc[m][n], 0, 0, 0);
        acc[m][n] = __builtin_amdgcn_mfma_f32_16x16x32_bf16(ah, bl[n], acc[m][n], 0, 0, 0);
        acc[m][n] = __builtin_amdgcn_mfma_f32_16x16x32_bf16(al, bh[n], acc[m][n], 0, 0, 0);
      }
    }
  }

  // epilogue: d = zn + cn - 2*dot - 0.8*sigmoid(adj[prev,col]); top-2 per row over this tile
  float cn[4];
#pragma unroll
  for (int n = 0; n < 4; ++n) cn[n] = cnorm[col0 + wc * 64 + n * 16 + lr];

#pragma unroll
  for (int m = 0; m < 4; ++m) {
#pragma unroll
    for (int reg = 0; reg < 4; ++reg) {
      const int rl = wr * 64 + m * 16 + lg * 4 + reg;
      const int row = row0 + rl;
      const float zn = znorm[row];
      const int p = prev[row];
      float v1 = FLT_BIG, v2 = FLT_BIG;
      int i1 = 0x7fffffff, i2 = 0x7fffffff;
#pragma unroll
      for (int n = 0; n < 4; ++n) {
        const int col = col0 + wc * 64 + n * 16 + lr;
        const float ad = adj[(size_t)p * NDIM + col];
        const float bias = 0.8f / (1.0f + __expf(-ad));
        const float dv = (zn + cn[n]) - 2.0f * acc[m][n][reg] - bias;
        top2_ins(v1, i1, v2, i2, dv, col);
      }
#pragma unroll
      for (int msk = 1; msk < 16; msk <<= 1) {
        const float o1 = __shfl_xor(v1, msk, 64); const int oi1 = __shfl_xor(i1, msk, 64);
        const float o2 = __shfl_xor(v2, msk, 64); const int oi2 = __shfl_xor(i2, msk, 64);
        top2_merge(v1, i1, v2, i2, o1, oi1, o2, oi2);
      }
      if (lr == 0) { sv1[wc][rl] = v1; si1[wc][rl] = i1; sv2[wc][rl] = v2; si2[wc][rl] = i2; }
    }
  }
  __syncthreads();
  if (tid < 128) {
    float v1 = sv1[0][tid], v2 = sv2[0][tid];
    int i1 = si1[0][tid], i2 = si2[0][tid];
    top2_merge(v1, i1, v2, i2, sv1[1][tid], si1[1][tid], sv2[1][tid], si2[1][tid]);
    const size_t o = (size_t)(row0 + tid) * 64 + bn;
    wsv1[o] = v1; wsi1[o] = i1; wsv2[o] = v2; wsi2[o] = i2;
  }
}

// global top-2 over the 64 column tiles (one wave per row)
__global__ __launch_bounds__(64)
void argmin_reduce2(const float* __restrict__ wsv1, const int* __restrict__ wsi1,
                    const float* __restrict__ wsv2, const int* __restrict__ wsi2,
                    float* __restrict__ gv1, int* __restrict__ gi1,
                    float* __restrict__ gv2, int* __restrict__ gi2) {
  const int row = blockIdx.x;
  const int t = threadIdx.x;  // 64
  const size_t o = (size_t)row * 64 + t;
  float v1 = wsv1[o], v2 = wsv2[o];
  int i1 = wsi1[o], i2 = wsi2[o];
  for (int m = 1; m < 64; m <<= 1) {
    const float o1 = __shfl_xor(v1, m, 64); const int oi1 = __shfl_xor(i1, m, 64);
    const float o2 = __shfl_xor(v2, m, 64); const int oi2 = __shfl_xor(i2, m, 64);
    top2_merge(v1, i1, v2, i2, o1, oi1, o2, oi2);
  }
  if (t == 0) { gv1[row] = v1; gi1[row] = i1; gv2[row] = v2; gi2[row] = i2; }
}

// exact fp32 recompute of the top-2 candidates when the approximate gap is small
__global__ __launch_bounds__(128)
void refine_kernel(const float* __restrict__ gw_real, const float* __restrict__ gw_imag,
                   const float* __restrict__ codebook, const int* __restrict__ prev,
                   const float* __restrict__ adj, const float* __restrict__ znorm,
                   const float* __restrict__ cnorm,
                   const float* __restrict__ gv1, const int* __restrict__ gi1,
                   const float* __restrict__ gv2, const int* __restrict__ gi2,
                   float* __restrict__ out, float* __restrict__ minfinal,
                   int* __restrict__ idxfinal) {
  __shared__ float r1[128], r2[128];
  const int row = blockIdx.x;
  const int t = threadIdx.x;
  const float v1 = gv1[row]; const int i1 = gi1[row];
  const float v2 = gv2[row]; const int i2 = gi2[row];
  if (v2 - v1 > EPS_REFINE) {
    if (t == 0) {
      out[OFF_IDX + row] = (float)i1;
      minfinal[row] = v1;
      idxfinal[row] = i1;
    }
    return;
  }
  const int k = t * 8;
  const float* zp = (k < LDIM) ? gw_real + (size_t)row * LDIM + k
                               : gw_imag + (size_t)row * LDIM + (k - LDIM);
  const float4 za = *reinterpret_cast<const float4*>(zp);
  const float4 zb = *reinterpret_cast<const float4*>(zp + 4);
  const float* c1p = codebook + (size_t)i1 * DDIM + k;
  const float* c2p = codebook + (size_t)i2 * DDIM + k;
  const float4 c1a = *reinterpret_cast<const float4*>(c1p);
  const float4 c1b = *reinterpret_cast<const float4*>(c1p + 4);
  const float4 c2a = *reinterpret_cast<const float4*>(c2p);
  const float4 c2b = *reinterpret_cast<const float4*>(c2p + 4);
  r1[t] = za.x*c1a.x + za.y*c1a.y + za.z*c1a.z + za.w*c1a.w
        + zb.x*c1b.x + zb.y*c1b.y + zb.z*c1b.z + zb.w*c1b.w;
  r2[t] = za.x*c2a.x + za.y*c2a.y + za.z*c2a.z + za.w*c2a.w
        + zb.x*c2b.x + zb.y*c2b.y + zb.z*c2b.z + zb.w*c2b.w;
  __syncthreads();
  for (int s = 64; s > 0; s >>= 1) {
    if (t < s) { r1[t] += r1[t + s]; r2[t] += r2[t + s]; }
    __syncthreads();
  }
  if (t == 0) {
    const int p = prev[row];
    const float zn = znorm[row];
    const float e1 = zn + cnorm[i1] - 2.0f * r1[0]
                   - 0.8f / (1.0f + expf(-adj[(size_t)p * NDIM + i1]));
    const float e2 = zn + cnorm[i2] - 2.0f * r2[0]
                   - 0.8f / (1.0f + expf(-adj[(size_t)p * NDIM + i2]));
    float wv; int wi;
    if (e2 < e1 || (e2 == e1 && i2 < i1)) { wv = e2; wi = i2; }
    else { wv = e1; wi = i1; }
    out[OFF_IDX + row] = (float)wi;
    minfinal[row] = wv;
    idxfinal[row] = wi;
  }
}

// ============ SHARED EPILOGUE ============

__global__ __launch_bounds__(256)
void epilogue_kernel(const float* __restrict__ gw_real, const float* __restrict__ gw_imag,
                     const float* __restrict__ codebook,
                     const float* __restrict__ sal_w, const float* __restrict__ sal_b,
                     const float* __restrict__ conf_w, const float* __restrict__ conf_b,
                     const float* __restrict__ minfinal, const int* __restrict__ idxfinal,
                     float* __restrict__ out, float* __restrict__ rowloss) {
  const int row = blockIdx.x;
  const int t = threadIdx.x;
  const int k = t << 2;
  const int idx = idxfinal[row];
  const float4 q = *reinterpret_cast<const float4*>(codebook + (size_t)idx * DDIM + k);
  float4 z;
  if (k < LDIM) z = *reinterpret_cast<const float4*>(gw_real + (size_t)row * LDIM + k);
  else          z = *reinterpret_cast<const float4*>(gw_imag + (size_t)row * LDIM + (k - LDIM));
  const float dx = q.x - z.x, dy = q.y - z.y, dz = q.z - z.z, dw = q.w - z.w;
  float4 st;
  st.x = z.x + dx; st.y = z.y + dy; st.z = z.z + dz; st.w = z.w + dw;
  float* dst = (k < LDIM) ? (out + OFF_REAL + (size_t)row * LDIM + k)
                          : (out + OFF_IMAG + (size_t)row * LDIM + (k - LDIM));
  *reinterpret_cast<float4*>(dst) = st;
  const float4 sw = *reinterpret_cast<const float4*>(sal_w + k);
  const float4 cw = *reinterpret_cast<const float4*>(conf_w + k);
  const float sdot = st.x*sw.x + st.y*sw.y + st.z*sw.z + st.w*sw.w;
  const float cdot = st.x*cw.x + st.y*cw.y + st.z*cw.z + st.w*cw.w;
  const float dif = dx*dx + dy*dy + dz*dz + dw*dw;
  __shared__ float r1[256], r2[256], r3[256];
  r1[t] = sdot; r2[t] = cdot; r3[t] = dif;
  __syncthreads();
  for (int s = 128; s > 0; s >>= 1) {
    if (t < s) { r1[t] += r1[t + s]; r2[t] += r2[t + s]; r3[t] += r3[t + s]; }
    __syncthreads();
  }
  if (t == 0) {
    out[OFF_SAL + row]  = r1[0] + sal_b[0] + 0.1f * (-minfinal[row]);
    out[OFF_CONF + row] = 1.0f / (1.0f + expf(-(r2[0] + conf_b[0])));
    rowloss[row] = r3[0];
  }
}

__global__ __launch_bounds__(256)
void loss_kernel(const float* __restrict__ rowloss, float* __restrict__ out) {
  const int t = threadIdx.x;
  float s = 0.f;
  for (int i = t; i < RDIM; i += 256) s += rowloss[i];
  __shared__ float red[256];
  red[t] = s;
  __syncthreads();
  for (int st = 128; st > 0; st >>= 1) {
    if (t < st) red[t] += red[t + st];
    __syncthreads();
  }
  if (t == 0) {
    const float m = red[0] / (float)((size_t)RDIM * DDIM);
    out[OFF_LOSS] = m + 0.01f * m;
  }
}

// ============ FALLBACK (round-1 fp32 path) ============

__global__ __launch_bounds__(256)
void norms_kernel(const float* __restrict__ gw_real, const float* __restrict__ gw_imag,
                  const float* __restrict__ codebook,
                  float* __restrict__ znorm, float* __restrict__ cnorm) {
  const int id = blockIdx.x;
  const int t = threadIdx.x;
  float s;
  if (id < RDIM) {
    const float4* zr = reinterpret_cast<const float4*>(gw_real + (size_t)id * LDIM);
    const float4* zi = reinterpret_cast<const float4*>(gw_imag + (size_t)id * LDIM);
    const float4 v = (t < 128) ? zr[t] : zi[t - 128];
    s = v.x*v.x + v.y*v.y + v.z*v.z + v.w*v.w;
  } else {
    const float4* c = reinterpret_cast<const float4*>(codebook + (size_t)(id - RDIM) * DDIM);
    const float4 v = c[t];
    s = v.x*v.x + v.y*v.y + v.z*v.z + v.w*v.w;
  }
  __shared__ float red[256];
  red[t] = s;
  __syncthreads();
  for (int st = 128; st > 0; st >>= 1) {
    if (t < st) red[t] += red[t + st];
    __syncthreads();
  }
  if (t == 0) {
    if (id < RDIM) znorm[id] = red[0];
    else           cnorm[id - RDIM] = red[0];
  }
}

__global__ __launch_bounds__(256)
void dist_kernel(const float* __restrict__ gw_real, const float* __restrict__ gw_imag,
                 const float* __restrict__ codebook, const int* __restrict__ prev,
                 const float* __restrict__ adj, const float* __restrict__ znorm,
                 const float* __restrict__ cnorm,
                 float* __restrict__ ws_min, int* __restrict__ ws_idx) {
  __shared__ float As[16][64];
  __shared__ float Bs[16][64];
  __shared__ int prevs[64];
  const int bm = blockIdx.x, bn = blockIdx.y;
  const int row0 = bm * 64, col0 = bn * 64;
  const int tid = threadIdx.x;
  const int tx = tid & 15, ty = tid >> 4;
  if (tid < 64) prevs[tid] = prev[row0 + tid];
  const int lm = tid >> 2;
  const int lk = (tid & 3) << 2;
  const int arow = row0 + lm;
  const int brow = col0 + lm;
  float acc[4][4] = {{0.f,0.f,0.f,0.f},{0.f,0.f,0.f,0.f},{0.f,0.f,0.f,0.f},{0.f,0.f,0.f,0.f}};
  for (int kk = 0; kk < DDIM; kk += 16) {
    const int k = kk + lk;
    float4 a, b;
    if (k < LDIM) a = *reinterpret_cast<const float4*>(gw_real + (size_t)arow * LDIM + k);
    else          a = *reinterpret_cast<const float4*>(gw_imag + (size_t)arow * LDIM + (k - LDIM));
    b = *reinterpret_cast<const float4*>(codebook + (size_t)brow * DDIM + k);
    __syncthreads();
    As[lk+0][lm]=a.x; As[lk+1][lm]=a.y; As[lk+2][lm]=a.z; As[lk+3][lm]=a.w;
    Bs[lk+0][lm]=b.x; Bs[lk+1][lm]=b.y; Bs[lk+2][lm]=b.z; Bs[lk+3][lm]=b.w;
    __syncthreads();
#pragma unroll
    for (int k2 = 0; k2 < 16; ++k2) {
      const float4 a4 = *reinterpret_cast<const float4*>(&As[k2][ty << 2]);
      const float4 b4 = *reinterpret_cast<const float4*>(&Bs[k2][tx << 2]);
      const float av[4] = {a4.x, a4.y, a4.z, a4.w};
      const float bv[4] = {b4.x, b4.y, b4.z, b4.w};
#pragma unroll
      for (int i = 0; i < 4; ++i)
#pragma unroll
        for (int j = 0; j < 4; ++j)
          acc[i][j] = fmaf(av[i], bv[j], acc[i][j]);
    }
  }
  const float4 cn4 = *reinterpret_cast<const float4*>(cnorm + col0 + (tx << 2));
  const float cnv[4] = {cn4.x, cn4.y, cn4.z, cn4.w};
#pragma unroll
  for (int i = 0; i < 4; ++i) {
    const int rsub = (ty << 2) + i;
    const int row = row0 + rsub;
    const float zn = znorm[row];
    const int p = prevs[rsub];
    const float4 ad4 = *reinterpret_cast<const float4*>(adj + (size_t)p * NDIM + col0 + (tx << 2));
    const float adv[4] = {ad4.x, ad4.y, ad4.z, ad4.w};
    float bv = FLT_BIG;
    int bi = -1;
#pragma unroll
    for (int j = 0; j < 4; ++j) {
      const float bias = 0.8f * (1.0f / (1.0f + expf(-adv[j])));
      const float dv = (zn + cnv[j]) - 2.0f * acc[i][j] - bias;
      const int col = col0 + (tx << 2) + j;
      if (dv < bv) { bv = dv; bi = col; }
    }
    for (int m = 1; m < 16; m <<= 1) {
      const float ov = __shfl_xor(bv, m, 64);
      const int   oi = __shfl_xor(bi, m, 64);
      if (ov < bv || (ov == bv && oi < bi)) { bv = ov; bi = oi; }
    }
    if (tx == 0) {
      ws_min[(size_t)row * 128 + bn] = bv;
      ws_idx[(size_t)row * 128 + bn] = bi;
    }
  }
}

__global__ __launch_bounds__(128)
void argmin_reduce(const float* __restrict__ ws_min, const int* __restrict__ ws_idx,
                   float* __restrict__ out, float* __restrict__ minfinal,
                   int* __restrict__ idxfinal) {
  const int row = blockIdx.x;
  const int t = threadIdx.x;
  __shared__ float sv[128];
  __shared__ int   si[128];
  sv[t] = ws_min[(size_t)row * 128 + t];
  si[t] = ws_idx[(size_t)row * 128 + t];
  __syncthreads();
  for (int s = 64; s > 0; s >>= 1) {
    if (t < s) {
      const float ov = sv[t + s];
      const int   oi = si[t + s];
      if (ov < sv[t] || (ov == sv[t] && oi < si[t])) { sv[t] = ov; si[t] = oi; }
    }
    __syncthreads();
  }
  if (t == 0) {
    out[OFF_IDX + row] = (float)si[0];
    minfinal[row] = sv[0];
    idxfinal[row] = si[0];
  }
}

// ============ HOST ============

extern "C" void kernel_launch(void* const* d_in, const int* in_sizes, int n_in,
                              void* d_out, int out_size, void* d_ws, size_t ws_size,
                              hipStream_t stream) {
  const float* gw_real  = (const float*)d_in[0];
  const float* gw_imag  = (const float*)d_in[1];
  const int*   prev     = (const int*)d_in[2];
  const float* codebook = (const float*)d_in[3];
  const float* adj      = (const float*)d_in[4];
  const float* sal_w    = (const float*)d_in[5];
  const float* sal_b    = (const float*)d_in[6];
  const float* conf_w   = (const float*)d_in[7];
  const float* conf_b   = (const float*)d_in[8];
  float* out = (float*)d_out;
  char* ws = (char*)d_ws;

  const size_t splitsz = (size_t)RDIM * DDIM;           // elements per split matrix
  const size_t tilesz  = (size_t)RDIM * 64;             // top-2-per-tile arrays
  size_t need = 4 * splitsz * 2                          // zhi,zlo,chi,clo (bf16)
              + 4 * tilesz * 4                           // wsv1,wsi1,wsv2,wsi2
              + 4 * (size_t)RDIM * 4                     // gv1,gi1,gv2,gi2
              + 5 * (size_t)RDIM * 4 + 4096;             // znorm,cnorm,minfinal,idxfinal,rowloss

  if (ws_size >= need) {
    unsigned short* zhi = (unsigned short*)ws;
    unsigned short* zlo = zhi + splitsz;
    unsigned short* chi = zlo + splitsz;
    unsigned short* clo = chi + splitsz;
    float* wsv1 = (float*)(clo + splitsz);
    int*   wsi1 = (int*)(wsv1 + tilesz);
    float* wsv2 = (float*)(wsi1 + tilesz);
    int*   wsi2 = (int*)(wsv2 + tilesz);
    float* gv1  = (float*)(wsi2 + tilesz);
    int*   gi1  = (int*)(gv1 + RDIM);
    float* gv2  = (float*)(gi1 + RDIM);
    int*   gi2  = (int*)(gv2 + RDIM);
    float* znorm    = (float*)(gi2 + RDIM);
    float* cnorm    = znorm + RDIM;
    float* minfinal = cnorm + NDIM;
    int*   idxfinal = (int*)(minfinal + RDIM);
    float* rowloss  = (float*)(idxfinal + RDIM);

    split_norms_kernel<<<RDIM + NDIM, 256, 0, stream>>>(gw_real, gw_imag, codebook,
                                                        zhi, zlo, chi, clo, znorm, cnorm);
    dist_mfma_kernel<<<dim3(64, 64), 256, 0, stream>>>(zhi, zlo, chi, clo, prev, adj,
                                                       znorm, cnorm, wsv1, wsi1, wsv2, wsi2);
    argmin_reduce2<<<RDIM, 64, 0, stream>>>(wsv1, wsi1, wsv2, wsi2, gv1, gi1, gv2, gi2);
    refine_kernel<<<RDIM, 128, 0, stream>>>(gw_real, gw_imag, codebook, prev, adj,
                                            znorm, cnorm, gv1, gi1, gv2, gi2,
                                            out, minfinal, idxfinal);
    epilogue_kernel<<<RDIM, 256, 0, stream>>>(gw_real, gw_imag, codebook, sal_w, sal_b,
                                              conf_w, conf_b, minfinal, idxfinal, out, rowloss);
    loss_kernel<<<1, 256, 0, stream>>>(rowloss, out);
  } else {
    float* ws_min   = (float*)ws;
    int*   ws_idx   = (int*)(ws + (size_t)RDIM * 128 * 4);
    float* znorm    = (float*)(ws + (size_t)RDIM * 128 * 8);
    float* cnorm    = znorm + RDIM;
    float* minfinal = cnorm + NDIM;
    int*   idxfinal = (int*)(minfinal + RDIM);
    float* rowloss  = (float*)(idxfinal + RDIM);

    norms_kernel<<<RDIM + NDIM, 256, 0, stream>>>(gw_real, gw_imag, codebook, znorm, cnorm);
    dist_kernel<<<dim3(RDIM / 64, NDIM / 64), 256, 0, stream>>>(
        gw_real, gw_imag, codebook, prev, adj, znorm, cnorm, ws_min, ws_idx);
    argmin_reduce<<<RDIM, 128, 0, stream>>>(ws_min, ws_idx, out, minfinal, idxfinal);
    epilogue_kernel<<<RDIM, 256, 0, stream>>>(gw_real, gw_imag, codebook, sal_w, sal_b,
                                              conf_w, conf_b, minfinal, idxfinal, out, rowloss);
    loss_kernel<<<1, 256, 0, stream>>>(rowloss, out);
  }
}

// Round 3
// 898.346 us; speedup vs baseline: 2.4432x; 1.0132x over previous
//
#include <hip/hip_runtime.h>
#include <math.h>

#define RDIM 8192   // B*S
#define DDIM 1024   // 2*L
#define NDIM 8192
#define LDIM 512
#define KCAT 3072   // folded split-GEMM K
#define KROW 2048   // stored row width of zcat/ccat

#define OFF_REAL 0
#define OFF_IMAG 4194304
#define OFF_SAL  8388608
#define OFF_CONF 8396800
#define OFF_LOSS 8404992
#define OFF_IDX  8404993

#define EPS_REFINE 0.02f
#define FLT_BIG 3.4e38f

typedef __attribute__((ext_vector_type(8))) short bf16x8;
typedef __attribute__((ext_vector_type(4))) float f32x4;

__device__ __forceinline__ unsigned short f2bf(float x) {
  unsigned u = __builtin_bit_cast(unsigned, x);
  unsigned r = (u + 0x7fff + ((u >> 16) & 1)) >> 16;
  return (unsigned short)r;
}
__device__ __forceinline__ float bf2f(unsigned short h) {
  unsigned u = ((unsigned)h) << 16;
  return __builtin_bit_cast(float, u);
}

__device__ __forceinline__ void load_lds16(const void* g, void* l) {
  __builtin_amdgcn_global_load_lds((const __attribute__((address_space(1))) void*)g,
                                   (__attribute__((address_space(3))) void*)l, 16, 0, 0);
}

__device__ __forceinline__ void top2_ins(float& v1, int& i1, float& v2, int& i2,
                                         float d, int c) {
  if (d < v1 || (d == v1 && c < i1)) { v2 = v1; i2 = i1; v1 = d; i1 = c; }
  else if (d < v2 || (d == v2 && c < i2)) { v2 = d; i2 = c; }
}
__device__ __forceinline__ void top2_merge(float& v1, int& i1, float& v2, int& i2,
                                           float o1, int oi1, float o2, int oi2) {
  if (o1 < v1 || (o1 == v1 && oi1 < i1)) {
    float t = v1; int ti = i1;
    v1 = o1; i1 = oi1;
    if (o2 < t || (o2 == t && oi2 < ti)) { v2 = o2; i2 = oi2; }
    else { v2 = t; i2 = ti; }
  } else {
    if (o1 < v2 || (o1 == v2 && oi1 < i2)) { v2 = o1; i2 = oi1; }
  }
}

// ============ split + norms: zcat=[zhi|zlo], ccat=[chi|clo] (bf16, row width 2048) ============
__global__ __launch_bounds__(256)
void split_norms_kernel(const float* __restrict__ gw_real, const float* __restrict__ gw_imag,
                        const float* __restrict__ codebook,
                        unsigned short* __restrict__ zcat, unsigned short* __restrict__ ccat,
                        float* __restrict__ znorm, float* __restrict__ cnorm) {
  const int id = blockIdx.x;   // [0, 16384)
  const int t = threadIdx.x;   // 256
  float4 v;
  unsigned short* dst;
  size_t off;
  if (id < RDIM) {
    v = (t < 128) ? reinterpret_cast<const float4*>(gw_real + (size_t)id * LDIM)[t]
                  : reinterpret_cast<const float4*>(gw_imag + (size_t)id * LDIM)[t - 128];
    dst = zcat; off = (size_t)id * KROW + t * 4;
  } else {
    const int n = id - RDIM;
    v = reinterpret_cast<const float4*>(codebook + (size_t)n * DDIM)[t];
    dst = ccat; off = (size_t)n * KROW + t * 4;
  }
  const float f[4] = {v.x, v.y, v.z, v.w};
  unsigned short hs[4], ls[4];
#pragma unroll
  for (int i = 0; i < 4; ++i) {
    hs[i] = f2bf(f[i]);
    ls[i] = f2bf(f[i] - bf2f(hs[i]));
  }
  *reinterpret_cast<ushort4*>(dst + off)        = make_ushort4(hs[0], hs[1], hs[2], hs[3]);
  *reinterpret_cast<ushort4*>(dst + off + DDIM) = make_ushort4(ls[0], ls[1], ls[2], ls[3]);
  float s = v.x*v.x + v.y*v.y + v.z*v.z + v.w*v.w;
  __shared__ float red[256];
  red[t] = s;
  __syncthreads();
  for (int st = 128; st > 0; st >>= 1) {
    if (t < st) red[t] += red[t + st];
    __syncthreads();
  }
  if (t == 0) {
    if (id < RDIM) znorm[id] = red[0];
    else           cnorm[id - RDIM] = red[0];
  }
}

// ============ 128x128 tile, K=3072 folded bf16 GEMM + fused bias/top-2 ============
__global__ __launch_bounds__(256)
void dist_mfma_kernel(const unsigned short* __restrict__ zcat, const unsigned short* __restrict__ ccat,
                      const int* __restrict__ prev, const float* __restrict__ adj,
                      const float* __restrict__ znorm, const float* __restrict__ cnorm,
                      float* __restrict__ wsv1, int* __restrict__ wsi1,
                      float* __restrict__ wsv2, int* __restrict__ wsi2) {
  __shared__ unsigned short tA[4096];   // [128][32] swizzled (chunk ^= (row>>1)&3)
  __shared__ unsigned short tB[4096];
  __shared__ float sv1[2][128], sv2[2][128];
  __shared__ int   si1[2][128], si2[2][128];

  const int bm = blockIdx.x, bn = blockIdx.y;
  const int row0 = bm * 128, col0 = bn * 128;
  const int tid = threadIdx.x;
  const int w = tid >> 6, l = tid & 63;
  const int wr = w >> 1, wc = w & 1;
  const int lr = l & 15, lg = l >> 4;

  // staging: physical chunk idx -> pre-swizzled global source chunk (rule #21, verified r2)
  const int idx0 = w * 128 + l;
  const int idx1 = idx0 + 64;
  const int r0_ = idx0 >> 2, r1_ = idx1 >> 2;
  const int lc0 = (idx0 & 3) ^ ((r0_ >> 1) & 3);
  const int lc1 = (idx1 & 3) ^ ((r1_ >> 1) & 3);
  const size_t zo0 = (size_t)(row0 + r0_) * KROW + lc0 * 8;
  const size_t zo1 = (size_t)(row0 + r1_) * KROW + lc1 * 8;
  const size_t co0 = (size_t)(col0 + r0_) * KROW + lc0 * 8;
  const size_t co1 = (size_t)(col0 + r1_) * KROW + lc1 * 8;
  unsigned short* const ldsA0 = &tA[w * 1024];
  unsigned short* const ldsB0 = &tB[w * 1024];

  const int swz = (lr >> 1) & 3;
  const int cpa = lg ^ swz;
  const int fragoff = lr * 32 + cpa * 8;

  f32x4 acc[4][4];
#pragma unroll
  for (int m = 0; m < 4; ++m)
#pragma unroll
    for (int n = 0; n < 4; ++n)
      acc[m][n] = (f32x4){0.f, 0.f, 0.f, 0.f};

  for (int kk = 0; kk < KCAT; kk += 32) {
    // uniform K remap: A' = [zhi|zhi|zlo], B' = [chi|clo|chi] over stored [hi|lo]
    const int kA = kk - ((kk >= 1024) ? 1024 : 0);
    const int kB = kk - ((kk >= 2048) ? 2048 : 0);
    __syncthreads();
    load_lds16(zcat + zo0 + kA, ldsA0);
    load_lds16(zcat + zo1 + kA, ldsA0 + 512);
    load_lds16(ccat + co0 + kB, ldsB0);
    load_lds16(ccat + co1 + kB, ldsB0 + 512);
    __syncthreads();

    bf16x8 bfr[4];
#pragma unroll
    for (int n = 0; n < 4; ++n)
      bfr[n] = *reinterpret_cast<const bf16x8*>(&tB[(wc * 64 + n * 16) * 32 + fragoff]);
#pragma unroll
    for (int m = 0; m < 4; ++m) {
      const bf16x8 afr = *reinterpret_cast<const bf16x8*>(&tA[(wr * 64 + m * 16) * 32 + fragoff]);
#pragma unroll
      for (int n = 0; n < 4; ++n)
        acc[m][n] = __builtin_amdgcn_mfma_f32_16x16x32_bf16(afr, bfr[n], acc[m][n], 0, 0, 0);
    }
  }

  // epilogue: d = zn + cn - 2*dot - 0.8*sigmoid(adj[prev,col]); top-2 per row over this tile
  float cn[4];
#pragma unroll
  for (int n = 0; n < 4; ++n) cn[n] = cnorm[col0 + wc * 64 + n * 16 + lr];

#pragma unroll
  for (int m = 0; m < 4; ++m) {
#pragma unroll
    for (int reg = 0; reg < 4; ++reg) {
      const int rl = wr * 64 + m * 16 + lg * 4 + reg;
      const int row = row0 + rl;
      const float zn = znorm[row];
      const int p = prev[row];
      float v1 = FLT_BIG, v2 = FLT_BIG;
      int i1 = 0x7fffffff, i2 = 0x7fffffff;
#pragma unroll
      for (int n = 0; n < 4; ++n) {
        const int col = col0 + wc * 64 + n * 16 + lr;
        const float ad = adj[(size_t)p * NDIM + col];
        const float bias = 0.8f / (1.0f + __expf(-ad));
        const float dv = (zn + cn[n]) - 2.0f * acc[m][n][reg] - bias;
        top2_ins(v1, i1, v2, i2, dv, col);
      }
#pragma unroll
      for (int msk = 1; msk < 16; msk <<= 1) {
        const float o1 = __shfl_xor(v1, msk, 64); const int oi1 = __shfl_xor(i1, msk, 64);
        const float o2 = __shfl_xor(v2, msk, 64); const int oi2 = __shfl_xor(i2, msk, 64);
        top2_merge(v1, i1, v2, i2, o1, oi1, o2, oi2);
      }
      if (lr == 0) { sv1[wc][rl] = v1; si1[wc][rl] = i1; sv2[wc][rl] = v2; si2[wc][rl] = i2; }
    }
  }
  __syncthreads();
  if (tid < 128) {
    float v1 = sv1[0][tid], v2 = sv2[0][tid];
    int i1 = si1[0][tid], i2 = si2[0][tid];
    top2_merge(v1, i1, v2, i2, sv1[1][tid], si1[1][tid], sv2[1][tid], si2[1][tid]);
    const size_t o = (size_t)(row0 + tid) * 64 + bn;
    wsv1[o] = v1; wsi1[o] = i1; wsv2[o] = v2; wsi2[o] = i2;
  }
}

// global top-2 over the 64 column tiles (one wave per row)
__global__ __launch_bounds__(64)
void argmin_reduce2(const float* __restrict__ wsv1, const int* __restrict__ wsi1,
                    const float* __restrict__ wsv2, const int* __restrict__ wsi2,
                    float* __restrict__ gv1, int* __restrict__ gi1,
                    float* __restrict__ gv2, int* __restrict__ gi2) {
  const int row = blockIdx.x;
  const int t = threadIdx.x;  // 64
  const size_t o = (size_t)row * 64 + t;
  float v1 = wsv1[o], v2 = wsv2[o];
  int i1 = wsi1[o], i2 = wsi2[o];
  for (int m = 1; m < 64; m <<= 1) {
    const float o1 = __shfl_xor(v1, m, 64); const int oi1 = __shfl_xor(i1, m, 64);
    const float o2 = __shfl_xor(v2, m, 64); const int oi2 = __shfl_xor(i2, m, 64);
    top2_merge(v1, i1, v2, i2, o1, oi1, o2, oi2);
  }
  if (t == 0) { gv1[row] = v1; gi1[row] = i1; gv2[row] = v2; gi2[row] = i2; }
}

// exact fp32 recompute of the top-2 candidates when the approximate gap is small
__global__ __launch_bounds__(128)
void refine_kernel(const float* __restrict__ gw_real, const float* __restrict__ gw_imag,
                   const float* __restrict__ codebook, const int* __restrict__ prev,
                   const float* __restrict__ adj, const float* __restrict__ znorm,
                   const float* __restrict__ cnorm,
                   const float* __restrict__ gv1, const int* __restrict__ gi1,
                   const float* __restrict__ gv2, const int* __restrict__ gi2,
                   float* __restrict__ out, float* __restrict__ minfinal,
                   int* __restrict__ idxfinal) {
  __shared__ float r1[128], r2[128];
  const int row = blockIdx.x;
  const int t = threadIdx.x;
  const float v1 = gv1[row]; const int i1 = gi1[row];
  const float v2 = gv2[row]; const int i2 = gi2[row];
  if (v2 - v1 > EPS_REFINE) {
    if (t == 0) {
      out[OFF_IDX + row] = (float)i1;
      minfinal[row] = v1;
      idxfinal[row] = i1;
    }
    return;
  }
  const int k = t * 8;
  const float* zp = (k < LDIM) ? gw_real + (size_t)row * LDIM + k
                               : gw_imag + (size_t)row * LDIM + (k - LDIM);
  const float4 za = *reinterpret_cast<const float4*>(zp);
  const float4 zb = *reinterpret_cast<const float4*>(zp + 4);
  const float* c1p = codebook + (size_t)i1 * DDIM + k;
  const float* c2p = codebook + (size_t)i2 * DDIM + k;
  const float4 c1a = *reinterpret_cast<const float4*>(c1p);
  const float4 c1b = *reinterpret_cast<const float4*>(c1p + 4);
  const float4 c2a = *reinterpret_cast<const float4*>(c2p);
  const float4 c2b = *reinterpret_cast<const float4*>(c2p + 4);
  r1[t] = za.x*c1a.x + za.y*c1a.y + za.z*c1a.z + za.w*c1a.w
        + zb.x*c1b.x + zb.y*c1b.y + zb.z*c1b.z + zb.w*c1b.w;
  r2[t] = za.x*c2a.x + za.y*c2a.y + za.z*c2a.z + za.w*c2a.w
        + zb.x*c2b.x + zb.y*c2b.y + zb.z*c2b.z + zb.w*c2b.w;
  __syncthreads();
  for (int s = 64; s > 0; s >>= 1) {
    if (t < s) { r1[t] += r1[t + s]; r2[t] += r2[t + s]; }
    __syncthreads();
  }
  if (t == 0) {
    const int p = prev[row];
    const float zn = znorm[row];
    const float e1 = zn + cnorm[i1] - 2.0f * r1[0]
                   - 0.8f / (1.0f + expf(-adj[(size_t)p * NDIM + i1]));
    const float e2 = zn + cnorm[i2] - 2.0f * r2[0]
                   - 0.8f / (1.0f + expf(-adj[(size_t)p * NDIM + i2]));
    float wv; int wi;
    if (e2 < e1 || (e2 == e1 && i2 < i1)) { wv = e2; wi = i2; }
    else { wv = e1; wi = i1; }
    out[OFF_IDX + row] = (float)wi;
    minfinal[row] = wv;
    idxfinal[row] = wi;
  }
}

// ============ SHARED EPILOGUE ============

__global__ __launch_bounds__(256)
void epilogue_kernel(const float* __restrict__ gw_real, const float* __restrict__ gw_imag,
                     const float* __restrict__ codebook,
                     const float* __restrict__ sal_w, const float* __restrict__ sal_b,
                     const float* __restrict__ conf_w, const float* __restrict__ conf_b,
                     const float* __restrict__ minfinal, const int* __restrict__ idxfinal,
                     float* __restrict__ out, float* __restrict__ rowloss) {
  const int row = blockIdx.x;
  const int t = threadIdx.x;
  const int k = t << 2;
  const int idx = idxfinal[row];
  const float4 q = *reinterpret_cast<const float4*>(codebook + (size_t)idx * DDIM + k);
  float4 z;
  if (k < LDIM) z = *reinterpret_cast<const float4*>(gw_real + (size_t)row * LDIM + k);
  else          z = *reinterpret_cast<const float4*>(gw_imag + (size_t)row * LDIM + (k - LDIM));
  const float dx = q.x - z.x, dy = q.y - z.y, dz = q.z - z.z, dw = q.w - z.w;
  float4 st;
  st.x = z.x + dx; st.y = z.y + dy; st.z = z.z + dz; st.w = z.w + dw;
  float* dst = (k < LDIM) ? (out + OFF_REAL + (size_t)row * LDIM + k)
                          : (out + OFF_IMAG + (size_t)row * LDIM + (k - LDIM));
  *reinterpret_cast<float4*>(dst) = st;
  const float4 sw = *reinterpret_cast<const float4*>(sal_w + k);
  const float4 cw = *reinterpret_cast<const float4*>(conf_w + k);
  const float sdot = st.x*sw.x + st.y*sw.y + st.z*sw.z + st.w*sw.w;
  const float cdot = st.x*cw.x + st.y*cw.y + st.z*cw.z + st.w*cw.w;
  const float dif = dx*dx + dy*dy + dz*dz + dw*dw;
  __shared__ float r1[256], r2[256], r3[256];
  r1[t] = sdot; r2[t] = cdot; r3[t] = dif;
  __syncthreads();
  for (int s = 128; s > 0; s >>= 1) {
    if (t < s) { r1[t] += r1[t + s]; r2[t] += r2[t + s]; r3[t] += r3[t + s]; }
    __syncthreads();
  }
  if (t == 0) {
    out[OFF_SAL + row]  = r1[0] + sal_b[0] + 0.1f * (-minfinal[row]);
    out[OFF_CONF + row] = 1.0f / (1.0f + expf(-(r2[0] + conf_b[0])));
    rowloss[row] = r3[0];
  }
}

__global__ __launch_bounds__(256)
void loss_kernel(const float* __restrict__ rowloss, float* __restrict__ out) {
  const int t = threadIdx.x;
  float s = 0.f;
  for (int i = t; i < RDIM; i += 256) s += rowloss[i];
  __shared__ float red[256];
  red[t] = s;
  __syncthreads();
  for (int st = 128; st > 0; st >>= 1) {
    if (t < st) red[t] += red[t + st];
    __syncthreads();
  }
  if (t == 0) {
    const float m = red[0] / (float)((size_t)RDIM * DDIM);
    out[OFF_LOSS] = m + 0.01f * m;
  }
}

// ============ FALLBACK (round-1 fp32 path) ============

__global__ __launch_bounds__(256)
void norms_kernel(const float* __restrict__ gw_real, const float* __restrict__ gw_imag,
                  const float* __restrict__ codebook,
                  float* __restrict__ znorm, float* __restrict__ cnorm) {
  const int id = blockIdx.x;
  const int t = threadIdx.x;
  float s;
  if (id < RDIM) {
    const float4* zr = reinterpret_cast<const float4*>(gw_real + (size_t)id * LDIM);
    const float4* zi = reinterpret_cast<const float4*>(gw_imag + (size_t)id * LDIM);
    const float4 v = (t < 128) ? zr[t] : zi[t - 128];
    s = v.x*v.x + v.y*v.y + v.z*v.z + v.w*v.w;
  } else {
    const float4* c = reinterpret_cast<const float4*>(codebook + (size_t)(id - RDIM) * DDIM);
    const float4 v = c[t];
    s = v.x*v.x + v.y*v.y + v.z*v.z + v.w*v.w;
  }
  __shared__ float red[256];
  red[t] = s;
  __syncthreads();
  for (int st = 128; st > 0; st >>= 1) {
    if (t < st) red[t] += red[t + st];
    __syncthreads();
  }
  if (t == 0) {
    if (id < RDIM) znorm[id] = red[0];
    else           cnorm[id - RDIM] = red[0];
  }
}

__global__ __launch_bounds__(256)
void dist_kernel(const float* __restrict__ gw_real, const float* __restrict__ gw_imag,
                 const float* __restrict__ codebook, const int* __restrict__ prev,
                 const float* __restrict__ adj, const float* __restrict__ znorm,
                 const float* __restrict__ cnorm,
                 float* __restrict__ ws_min, int* __restrict__ ws_idx) {
  __shared__ float As[16][64];
  __shared__ float Bs[16][64];
  __shared__ int prevs[64];
  const int bm = blockIdx.x, bn = blockIdx.y;
  const int row0 = bm * 64, col0 = bn * 64;
  const int tid = threadIdx.x;
  const int tx = tid & 15, ty = tid >> 4;
  if (tid < 64) prevs[tid] = prev[row0 + tid];
  const int lm = tid >> 2;
  const int lk = (tid & 3) << 2;
  const int arow = row0 + lm;
  const int brow = col0 + lm;
  float acc[4][4] = {{0.f,0.f,0.f,0.f},{0.f,0.f,0.f,0.f},{0.f,0.f,0.f,0.f},{0.f,0.f,0.f,0.f}};
  for (int kk = 0; kk < DDIM; kk += 16) {
    const int k = kk + lk;
    float4 a, b;
    if (k < LDIM) a = *reinterpret_cast<const float4*>(gw_real + (size_t)arow * LDIM + k);
    else          a = *reinterpret_cast<const float4*>(gw_imag + (size_t)arow * LDIM + (k - LDIM));
    b = *reinterpret_cast<const float4*>(codebook + (size_t)brow * DDIM + k);
    __syncthreads();
    As[lk+0][lm]=a.x; As[lk+1][lm]=a.y; As[lk+2][lm]=a.z; As[lk+3][lm]=a.w;
    Bs[lk+0][lm]=b.x; Bs[lk+1][lm]=b.y; Bs[lk+2][lm]=b.z; Bs[lk+3][lm]=b.w;
    __syncthreads();
#pragma unroll
    for (int k2 = 0; k2 < 16; ++k2) {
      const float4 a4 = *reinterpret_cast<const float4*>(&As[k2][ty << 2]);
      const float4 b4 = *reinterpret_cast<const float4*>(&Bs[k2][tx << 2]);
      const float av[4] = {a4.x, a4.y, a4.z, a4.w};
      const float bv[4] = {b4.x, b4.y, b4.z, b4.w};
#pragma unroll
      for (int i = 0; i < 4; ++i)
#pragma unroll
        for (int j = 0; j < 4; ++j)
          acc[i][j] = fmaf(av[i], bv[j], acc[i][j]);
    }
  }
  const float4 cn4 = *reinterpret_cast<const float4*>(cnorm + col0 + (tx << 2));
  const float cnv[4] = {cn4.x, cn4.y, cn4.z, cn4.w};
#pragma unroll
  for (int i = 0; i < 4; ++i) {
    const int rsub = (ty << 2) + i;
    const int row = row0 + rsub;
    const float zn = znorm[row];
    const int p = prevs[rsub];
    const float4 ad4 = *reinterpret_cast<const float4*>(adj + (size_t)p * NDIM + col0 + (tx << 2));
    const float adv[4] = {ad4.x, ad4.y, ad4.z, ad4.w};
    float bv = FLT_BIG;
    int bi = -1;
#pragma unroll
    for (int j = 0; j < 4; ++j) {
      const float bias = 0.8f * (1.0f / (1.0f + expf(-adv[j])));
      const float dv = (zn + cnv[j]) - 2.0f * acc[i][j] - bias;
      const int col = col0 + (tx << 2) + j;
      if (dv < bv) { bv = dv; bi = col; }
    }
    for (int m = 1; m < 16; m <<= 1) {
      const float ov = __shfl_xor(bv, m, 64);
      const int   oi = __shfl_xor(bi, m, 64);
      if (ov < bv || (ov == bv && oi < bi)) { bv = ov; bi = oi; }
    }
    if (tx == 0) {
      ws_min[(size_t)row * 128 + bn] = bv;
      ws_idx[(size_t)row * 128 + bn] = bi;
    }
  }
}

__global__ __launch_bounds__(128)
void argmin_reduce(const float* __restrict__ ws_min, const int* __restrict__ ws_idx,
                   float* __restrict__ out, float* __restrict__ minfinal,
                   int* __restrict__ idxfinal) {
  const int row = blockIdx.x;
  const int t = threadIdx.x;
  __shared__ float sv[128];
  __shared__ int   si[128];
  sv[t] = ws_min[(size_t)row * 128 + t];
  si[t] = ws_idx[(size_t)row * 128 + t];
  __syncthreads();
  for (int s = 64; s > 0; s >>= 1) {
    if (t < s) {
      const float ov = sv[t + s];
      const int   oi = si[t + s];
      if (ov < sv[t] || (ov == sv[t] && oi < si[t])) { sv[t] = ov; si[t] = oi; }
    }
    __syncthreads();
  }
  if (t == 0) {
    out[OFF_IDX + row] = (float)si[0];
    minfinal[row] = sv[0];
    idxfinal[row] = si[0];
  }
}

// ============ HOST ============

extern "C" void kernel_launch(void* const* d_in, const int* in_sizes, int n_in,
                              void* d_out, int out_size, void* d_ws, size_t ws_size,
                              hipStream_t stream) {
  const float* gw_real  = (const float*)d_in[0];
  const float* gw_imag  = (const float*)d_in[1];
  const int*   prev     = (const int*)d_in[2];
  const float* codebook = (const float*)d_in[3];
  const float* adj      = (const float*)d_in[4];
  const float* sal_w    = (const float*)d_in[5];
  const float* sal_b    = (const float*)d_in[6];
  const float* conf_w   = (const float*)d_in[7];
  const float* conf_b   = (const float*)d_in[8];
  float* out = (float*)d_out;
  char* ws = (char*)d_ws;

  const size_t catsz  = (size_t)RDIM * KROW;             // elements per concat matrix (bf16)
  const size_t tilesz = (size_t)RDIM * 64;               // top-2-per-tile arrays
  size_t need = 2 * catsz * 2                            // zcat, ccat (bf16)
              + 4 * tilesz * 4                           // wsv1,wsi1,wsv2,wsi2
              + 4 * (size_t)RDIM * 4                     // gv1,gi1,gv2,gi2
              + 5 * (size_t)RDIM * 4 + 4096;             // znorm,cnorm,minfinal,idxfinal,rowloss

  if (ws_size >= need) {
    unsigned short* zcat = (unsigned short*)ws;
    unsigned short* ccat = zcat + catsz;
    float* wsv1 = (float*)(ccat + catsz);
    int*   wsi1 = (int*)(wsv1 + tilesz);
    float* wsv2 = (float*)(wsi1 + tilesz);
    int*   wsi2 = (int*)(wsv2 + tilesz);
    float* gv1  = (float*)(wsi2 + tilesz);
    int*   gi1  = (int*)(gv1 + RDIM);
    float* gv2  = (float*)(gi1 + RDIM);
    int*   gi2  = (int*)(gv2 + RDIM);
    float* znorm    = (float*)(gi2 + RDIM);
    float* cnorm    = znorm + RDIM;
    float* minfinal = cnorm + NDIM;
    int*   idxfinal = (int*)(minfinal + RDIM);
    float* rowloss  = (float*)(idxfinal + RDIM);

    split_norms_kernel<<<RDIM + NDIM, 256, 0, stream>>>(gw_real, gw_imag, codebook,
                                                        zcat, ccat, znorm, cnorm);
    dist_mfma_kernel<<<dim3(64, 64), 256, 0, stream>>>(zcat, ccat, prev, adj,
                                                       znorm, cnorm, wsv1, wsi1, wsv2, wsi2);
    argmin_reduce2<<<RDIM, 64, 0, stream>>>(wsv1, wsi1, wsv2, wsi2, gv1, gi1, gv2, gi2);
    refine_kernel<<<RDIM, 128, 0, stream>>>(gw_real, gw_imag, codebook, prev, adj,
                                            znorm, cnorm, gv1, gi1, gv2, gi2,
                                            out, minfinal, idxfinal);
    epilogue_kernel<<<RDIM, 256, 0, stream>>>(gw_real, gw_imag, codebook, sal_w, sal_b,
                                              conf_w, conf_b, minfinal, idxfinal, out, rowloss);
    loss_kernel<<<1, 256, 0, stream>>>(rowloss, out);
  } else {
    float* ws_min   = (float*)ws;
    int*   ws_idx   = (int*)(ws + (size_t)RDIM * 128 * 4);
    float* znorm    = (float*)(ws + (size_t)RDIM * 128 * 8);
    float* cnorm    = znorm + RDIM;
    float* minfinal = cnorm + NDIM;
    int*   idxfinal = (int*)(minfinal + RDIM);
    float* rowloss  = (float*)(idxfinal + RDIM);

    norms_kernel<<<RDIM + NDIM, 256, 0, stream>>>(gw_real, gw_imag, codebook, znorm, cnorm);
    dist_kernel<<<dim3(RDIM / 64, NDIM / 64), 256, 0, stream>>>(
        gw_real, gw_imag, codebook, prev, adj, znorm, cnorm, ws_min, ws_idx);
    argmin_reduce<<<RDIM, 128, 0, stream>>>(ws_min, ws_idx, out, minfinal, idxfinal);
    epilogue_kernel<<<RDIM, 256, 0, stream>>>(gw_real, gw_imag, codebook, sal_w, sal_b,
                                              conf_w, conf_b, minfinal, idxfinal, out, rowloss);
    loss_kernel<<<1, 256, 0, stream>>>(rowloss, out);
  }
}

// Round 4
// 630.688 us; speedup vs baseline: 3.4801x; 1.4244x over previous
//
#include <hip/hip_runtime.h>
#include <math.h>

#define RDIM 8192   // B*S
#define DDIM 1024   // 2*L
#define NDIM 8192
#define LDIM 512
#define NSTEPS 32   // K-steps of 32 over K=1024

#define OFF_REAL 0
#define OFF_IMAG 4194304
#define OFF_SAL  8388608
#define OFF_CONF 8396800
#define OFF_LOSS 8404992
#define OFF_IDX  8404993

#define MARGIN 0.3f
#define MAXCAND 16
#define FLT_BIG 3.4e38f

typedef __attribute__((ext_vector_type(8))) short bf16x8;
typedef __attribute__((ext_vector_type(4))) float f32x4;

__device__ __forceinline__ unsigned short f2bf(float x) {
  unsigned u = __builtin_bit_cast(unsigned, x);
  unsigned r = (u + 0x7fff + ((u >> 16) & 1)) >> 16;
  return (unsigned short)r;
}

__device__ __forceinline__ void load_lds16(const void* g, void* l) {
  __builtin_amdgcn_global_load_lds((const __attribute__((address_space(1))) void*)g,
                                   (__attribute__((address_space(3))) void*)l, 16, 0, 0);
}

__device__ __forceinline__ void top2_ins(float& v1, int& i1, float& v2, int& i2,
                                         float d, int c) {
  if (d < v1 || (d == v1 && c < i1)) { v2 = v1; i2 = i1; v1 = d; i1 = c; }
  else if (d < v2 || (d == v2 && c < i2)) { v2 = d; i2 = c; }
}
__device__ __forceinline__ void top2_merge(float& v1, int& i1, float& v2, int& i2,
                                           float o1, int oi1, float o2, int oi2) {
  if (o1 < v1 || (o1 == v1 && oi1 < i1)) {
    float t = v1; int ti = i1;
    v1 = o1; i1 = oi1;
    if (o2 < t || (o2 == t && oi2 < ti)) { v2 = o2; i2 = oi2; }
    else { v2 = t; i2 = ti; }
  } else {
    if (o1 < v2 || (o1 == v2 && oi1 < i2)) { v2 = o1; i2 = oi1; }
  }
}

// ============ bf16 cast + exact fp32 norms ============
__global__ __launch_bounds__(256)
void split_norms_kernel(const float* __restrict__ gw_real, const float* __restrict__ gw_imag,
                        const float* __restrict__ codebook,
                        unsigned short* __restrict__ zh, unsigned short* __restrict__ ch,
                        float* __restrict__ znorm, float* __restrict__ cnorm) {
  const int id = blockIdx.x;   // [0, 16384)
  const int t = threadIdx.x;   // 256
  float4 v;
  unsigned short* dst;
  if (id < RDIM) {
    v = (t < 128) ? reinterpret_cast<const float4*>(gw_real + (size_t)id * LDIM)[t]
                  : reinterpret_cast<const float4*>(gw_imag + (size_t)id * LDIM)[t - 128];
    dst = zh;
  } else {
    v = reinterpret_cast<const float4*>(codebook + (size_t)(id - RDIM) * DDIM)[t];
    dst = ch;
  }
  const size_t off = (size_t)(id < RDIM ? id : id - RDIM) * DDIM + t * 4;
  *reinterpret_cast<ushort4*>(dst + off) =
      make_ushort4(f2bf(v.x), f2bf(v.y), f2bf(v.z), f2bf(v.w));
  float s = v.x*v.x + v.y*v.y + v.z*v.z + v.w*v.w;
  __shared__ float red[256];
  red[t] = s;
  __syncthreads();
  for (int st = 128; st > 0; st >>= 1) {
    if (t < st) red[t] += red[t + st];
    __syncthreads();
  }
  if (t == 0) {
    if (id < RDIM) znorm[id] = red[0];
    else           cnorm[id - RDIM] = red[0];
  }
}

// ============ 128x128 coarse bf16 GEMM, double-buffered, per-64col-half top-2 ============
__global__ __launch_bounds__(256)
void dist_mfma_kernel(const unsigned short* __restrict__ zh, const unsigned short* __restrict__ ch,
                      const int* __restrict__ prev, const float* __restrict__ adj,
                      const float* __restrict__ znorm, const float* __restrict__ cnorm,
                      float* __restrict__ wsv1, int* __restrict__ wsi1,
                      float* __restrict__ wsv2, int* __restrict__ wsi2) {
  __shared__ unsigned short tA[2][4096];   // [128][32] swizzled, double-buffered
  __shared__ unsigned short tB[2][4096];

  const int bm = blockIdx.x, bn = blockIdx.y;
  const int row0 = bm * 128, col0 = bn * 128;
  const int tid = threadIdx.x;
  const int w = tid >> 6, l = tid & 63;
  const int wr = w >> 1, wc = w & 1;
  const int lr = l & 15, lg = l >> 4;

  // staging: physical chunk idx -> pre-swizzled global source chunk (rule #21, verified r2/r3)
  const int idx0 = w * 128 + l;
  const int idx1 = idx0 + 64;
  const int r0_ = idx0 >> 2, r1_ = idx1 >> 2;
  const int lc0 = (idx0 & 3) ^ ((r0_ >> 1) & 3);
  const int lc1 = (idx1 & 3) ^ ((r1_ >> 1) & 3);
  const size_t zo0 = (size_t)(row0 + r0_) * DDIM + lc0 * 8;
  const size_t zo1 = (size_t)(row0 + r1_) * DDIM + lc1 * 8;
  const size_t co0 = (size_t)(col0 + r0_) * DDIM + lc0 * 8;
  const size_t co1 = (size_t)(col0 + r1_) * DDIM + lc1 * 8;
  const int woff = w * 1024;

  const int swz = (lr >> 1) & 3;
  const int cpa = lg ^ swz;
  const int fragoff = lr * 32 + cpa * 8;

  f32x4 acc[4][4];
#pragma unroll
  for (int m = 0; m < 4; ++m)
#pragma unroll
    for (int n = 0; n < 4; ++n)
      acc[m][n] = (f32x4){0.f, 0.f, 0.f, 0.f};

  // prologue: stage K-step 0 into buffer 0
  load_lds16(zh + zo0, &tA[0][woff]);
  load_lds16(zh + zo1, &tA[0][woff + 512]);
  load_lds16(ch + co0, &tB[0][woff]);
  load_lds16(ch + co1, &tB[0][woff + 512]);
  __syncthreads();

  for (int t = 0; t < NSTEPS; ++t) {
    const int cur = t & 1;
    if (t + 1 < NSTEPS) {               // issue next-tile loads BEFORE compute (T3)
      const int nxt = cur ^ 1;
      const int k = (t + 1) * 32;
      load_lds16(zh + zo0 + k, &tA[nxt][woff]);
      load_lds16(zh + zo1 + k, &tA[nxt][woff + 512]);
      load_lds16(ch + co0 + k, &tB[nxt][woff]);
      load_lds16(ch + co1 + k, &tB[nxt][woff + 512]);
    }
    bf16x8 bfr[4];
#pragma unroll
    for (int n = 0; n < 4; ++n)
      bfr[n] = *reinterpret_cast<const bf16x8*>(&tB[cur][(wc * 64 + n * 16) * 32 + fragoff]);
#pragma unroll
    for (int m = 0; m < 4; ++m) {
      const bf16x8 afr = *reinterpret_cast<const bf16x8*>(&tA[cur][(wr * 64 + m * 16) * 32 + fragoff]);
#pragma unroll
      for (int n = 0; n < 4; ++n)
        acc[m][n] = __builtin_amdgcn_mfma_f32_16x16x32_bf16(afr, bfr[n], acc[m][n], 0, 0, 0);
    }
    __syncthreads();   // drains stage(t+1) loads + protects buffer reuse
  }

  // epilogue: d = zn + cn - 2*dot - 0.8*sigmoid(adj[prev,col]); top-2 per row per 64-col half
  float cn[4];
#pragma unroll
  for (int n = 0; n < 4; ++n) cn[n] = cnorm[col0 + wc * 64 + n * 16 + lr];

#pragma unroll
  for (int m = 0; m < 4; ++m) {
#pragma unroll
    for (int reg = 0; reg < 4; ++reg) {
      const int rl = wr * 64 + m * 16 + lg * 4 + reg;
      const int row = row0 + rl;
      const float zn = znorm[row];
      const int p = prev[row];
      float v1 = FLT_BIG, v2 = FLT_BIG;
      int i1 = 0x7fffffff, i2 = 0x7fffffff;
#pragma unroll
      for (int n = 0; n < 4; ++n) {
        const int col = col0 + wc * 64 + n * 16 + lr;
        const float ad = adj[(size_t)p * NDIM + col];
        const float bias = 0.8f / (1.0f + __expf(-ad));
        const float dv = (zn + cn[n]) - 2.0f * acc[m][n][reg] - bias;
        top2_ins(v1, i1, v2, i2, dv, col);
      }
#pragma unroll
      for (int msk = 1; msk < 16; msk <<= 1) {
        const float o1 = __shfl_xor(v1, msk, 64); const int oi1 = __shfl_xor(i1, msk, 64);
        const float o2 = __shfl_xor(v2, msk, 64); const int oi2 = __shfl_xor(i2, msk, 64);
        top2_merge(v1, i1, v2, i2, o1, oi1, o2, oi2);
      }
      if (lr == 0) {
        const size_t o = (size_t)row * 128 + bn * 2 + wc;
        wsv1[o] = v1; wsi1[o] = i1; wsv2[o] = v2; wsi2[o] = i2;
      }
    }
  }
}

// ============ global argmin + candidate collection (one wave per row) ============
__global__ __launch_bounds__(64)
void argmin_collect(const float* __restrict__ wsv1, const int* __restrict__ wsi1,
                    const float* __restrict__ wsv2, const int* __restrict__ wsi2,
                    float* __restrict__ out, float* __restrict__ minfinal,
                    int* __restrict__ idxfinal,
                    int* __restrict__ gcount, int* __restrict__ gcand) {
  __shared__ int s_cnt;
  __shared__ int s_list[MAXCAND + 8];
  const int row = blockIdx.x;
  const int t = threadIdx.x;  // 64
  if (t == 0) s_cnt = 0;
  __syncthreads();
  const size_t o = (size_t)row * 128 + t;
  const float av1 = wsv1[o], av2 = wsv2[o];
  const int   ai1 = wsi1[o], ai2 = wsi2[o];
  const float bv1 = wsv1[o + 64], bv2 = wsv2[o + 64];
  const int   bi1 = wsi1[o + 64], bi2 = wsi2[o + 64];
  // lex-min over the 128 half-minima
  float mv = av1; int mi = ai1;
  if (bv1 < mv || (bv1 == mv && bi1 < mi)) { mv = bv1; mi = bi1; }
  for (int m = 1; m < 64; m <<= 1) {
    const float ov = __shfl_xor(mv, m, 64);
    const int   oi = __shfl_xor(mi, m, 64);
    if (ov < mv || (ov == mv && oi < mi)) { mv = ov; mi = oi; }
  }
  const float thr = mv + MARGIN;
  int c = (av1 <= thr) + (av2 <= thr) + (bv1 <= thr) + (bv2 <= thr);
  for (int m = 1; m < 64; m <<= 1) c += __shfl_xor(c, m, 64);
  // always publish the coarse winner (refine overwrites ambiguous rows)
  if (t == 0) {
    out[OFF_IDX + row] = (float)mi;
    minfinal[row] = mv;
    idxfinal[row] = mi;
  }
  if (c <= 1) {
    if (t == 0) gcount[row] = 1;
    return;
  }
  if (av1 <= thr) { int p = atomicAdd(&s_cnt, 1); if (p < MAXCAND) s_list[p] = ai1; }
  if (av2 <= thr) { int p = atomicAdd(&s_cnt, 1); if (p < MAXCAND) s_list[p] = ai2; }
  if (bv1 <= thr) { int p = atomicAdd(&s_cnt, 1); if (p < MAXCAND) s_list[p] = bi1; }
  if (bv2 <= thr) { int p = atomicAdd(&s_cnt, 1); if (p < MAXCAND) s_list[p] = bi2; }
  __syncthreads();
  const int k = (s_cnt < MAXCAND) ? s_cnt : MAXCAND;
  if (t == 0) gcount[row] = k;
  if (t < k) gcand[(size_t)row * MAXCAND + t] = s_list[t];
}

// ============ exact fp32 refine of ambiguous rows ============
__global__ __launch_bounds__(64)
void refine_kernel(const float* __restrict__ gw_real, const float* __restrict__ gw_imag,
                   const float* __restrict__ codebook, const int* __restrict__ prev,
                   const float* __restrict__ adj, const float* __restrict__ znorm,
                   const float* __restrict__ cnorm,
                   const int* __restrict__ gcount, const int* __restrict__ gcand,
                   float* __restrict__ out, float* __restrict__ minfinal,
                   int* __restrict__ idxfinal) {
  const int row = blockIdx.x;
  const int t = threadIdx.x;   // 64 lanes, 16 contiguous floats each
  const int K = gcount[row];
  if (K <= 1) return;
  const int base = t * 16;
  const float* zp = (base < LDIM) ? gw_real + (size_t)row * LDIM + base
                                  : gw_imag + (size_t)row * LDIM + (base - LDIM);
  float z[16];
#pragma unroll
  for (int q = 0; q < 4; ++q) {
    const float4 v = reinterpret_cast<const float4*>(zp)[q];
    z[q*4+0] = v.x; z[q*4+1] = v.y; z[q*4+2] = v.z; z[q*4+3] = v.w;
  }
  const float zn = znorm[row];
  const int p = prev[row];
  float bestd = FLT_BIG;
  int besti = 0x7fffffff;
  for (int j = 0; j < K; ++j) {
    const int idx = gcand[(size_t)row * MAXCAND + j];
    const float* cp = codebook + (size_t)idx * DDIM + base;
    float dot = 0.f;
#pragma unroll
    for (int q = 0; q < 4; ++q) {
      const float4 v = reinterpret_cast<const float4*>(cp)[q];
      dot += z[q*4+0]*v.x + z[q*4+1]*v.y + z[q*4+2]*v.z + z[q*4+3]*v.w;
    }
    for (int m = 1; m < 64; m <<= 1) dot += __shfl_xor(dot, m, 64);
    const float d = zn + cnorm[idx] - 2.0f * dot
                  - 0.8f / (1.0f + expf(-adj[(size_t)p * NDIM + idx]));
    if (d < bestd || (d == bestd && idx < besti)) { bestd = d; besti = idx; }
  }
  if (t == 0) {
    out[OFF_IDX + row] = (float)besti;
    minfinal[row] = bestd;
    idxfinal[row] = besti;
  }
}

// ============ SHARED EPILOGUE ============

__global__ __launch_bounds__(256)
void epilogue_kernel(const float* __restrict__ gw_real, const float* __restrict__ gw_imag,
                     const float* __restrict__ codebook,
                     const float* __restrict__ sal_w, const float* __restrict__ sal_b,
                     const float* __restrict__ conf_w, const float* __restrict__ conf_b,
                     const float* __restrict__ minfinal, const int* __restrict__ idxfinal,
                     float* __restrict__ out, float* __restrict__ rowloss) {
  const int row = blockIdx.x;
  const int t = threadIdx.x;
  const int k = t << 2;
  const int idx = idxfinal[row];
  const float4 q = *reinterpret_cast<const float4*>(codebook + (size_t)idx * DDIM + k);
  float4 z;
  if (k < LDIM) z = *reinterpret_cast<const float4*>(gw_real + (size_t)row * LDIM + k);
  else          z = *reinterpret_cast<const float4*>(gw_imag + (size_t)row * LDIM + (k - LDIM));
  const float dx = q.x - z.x, dy = q.y - z.y, dz = q.z - z.z, dw = q.w - z.w;
  float4 st;
  st.x = z.x + dx; st.y = z.y + dy; st.z = z.z + dz; st.w = z.w + dw;
  float* dst = (k < LDIM) ? (out + OFF_REAL + (size_t)row * LDIM + k)
                          : (out + OFF_IMAG + (size_t)row * LDIM + (k - LDIM));
  *reinterpret_cast<float4*>(dst) = st;
  const float4 sw = *reinterpret_cast<const float4*>(sal_w + k);
  const float4 cw = *reinterpret_cast<const float4*>(conf_w + k);
  const float sdot = st.x*sw.x + st.y*sw.y + st.z*sw.z + st.w*sw.w;
  const float cdot = st.x*cw.x + st.y*cw.y + st.z*cw.z + st.w*cw.w;
  const float dif = dx*dx + dy*dy + dz*dz + dw*dw;
  __shared__ float r1[256], r2[256], r3[256];
  r1[t] = sdot; r2[t] = cdot; r3[t] = dif;
  __syncthreads();
  for (int s = 128; s > 0; s >>= 1) {
    if (t < s) { r1[t] += r1[t + s]; r2[t] += r2[t + s]; r3[t] += r3[t + s]; }
    __syncthreads();
  }
  if (t == 0) {
    out[OFF_SAL + row]  = r1[0] + sal_b[0] + 0.1f * (-minfinal[row]);
    out[OFF_CONF + row] = 1.0f / (1.0f + expf(-(r2[0] + conf_b[0])));
    rowloss[row] = r3[0];
  }
}

__global__ __launch_bounds__(256)
void loss_kernel(const float* __restrict__ rowloss, float* __restrict__ out) {
  const int t = threadIdx.x;
  float s = 0.f;
  for (int i = t; i < RDIM; i += 256) s += rowloss[i];
  __shared__ float red[256];
  red[t] = s;
  __syncthreads();
  for (int st = 128; st > 0; st >>= 1) {
    if (t < st) red[t] += red[t + st];
    __syncthreads();
  }
  if (t == 0) {
    const float m = red[0] / (float)((size_t)RDIM * DDIM);
    out[OFF_LOSS] = m + 0.01f * m;
  }
}

// ============ FALLBACK (round-1 fp32 path) ============

__global__ __launch_bounds__(256)
void norms_kernel(const float* __restrict__ gw_real, const float* __restrict__ gw_imag,
                  const float* __restrict__ codebook,
                  float* __restrict__ znorm, float* __restrict__ cnorm) {
  const int id = blockIdx.x;
  const int t = threadIdx.x;
  float s;
  if (id < RDIM) {
    const float4* zr = reinterpret_cast<const float4*>(gw_real + (size_t)id * LDIM);
    const float4* zi = reinterpret_cast<const float4*>(gw_imag + (size_t)id * LDIM);
    const float4 v = (t < 128) ? zr[t] : zi[t - 128];
    s = v.x*v.x + v.y*v.y + v.z*v.z + v.w*v.w;
  } else {
    const float4* c = reinterpret_cast<const float4*>(codebook + (size_t)(id - RDIM) * DDIM);
    const float4 v = c[t];
    s = v.x*v.x + v.y*v.y + v.z*v.z + v.w*v.w;
  }
  __shared__ float red[256];
  red[t] = s;
  __syncthreads();
  for (int st = 128; st > 0; st >>= 1) {
    if (t < st) red[t] += red[t + st];
    __syncthreads();
  }
  if (t == 0) {
    if (id < RDIM) znorm[id] = red[0];
    else           cnorm[id - RDIM] = red[0];
  }
}

__global__ __launch_bounds__(256)
void dist_kernel(const float* __restrict__ gw_real, const float* __restrict__ gw_imag,
                 const float* __restrict__ codebook, const int* __restrict__ prev,
                 const float* __restrict__ adj, const float* __restrict__ znorm,
                 const float* __restrict__ cnorm,
                 float* __restrict__ ws_min, int* __restrict__ ws_idx) {
  __shared__ float As[16][64];
  __shared__ float Bs[16][64];
  __shared__ int prevs[64];
  const int bm = blockIdx.x, bn = blockIdx.y;
  const int row0 = bm * 64, col0 = bn * 64;
  const int tid = threadIdx.x;
  const int tx = tid & 15, ty = tid >> 4;
  if (tid < 64) prevs[tid] = prev[row0 + tid];
  const int lm = tid >> 2;
  const int lk = (tid & 3) << 2;
  const int arow = row0 + lm;
  const int brow = col0 + lm;
  float acc[4][4] = {{0.f,0.f,0.f,0.f},{0.f,0.f,0.f,0.f},{0.f,0.f,0.f,0.f},{0.f,0.f,0.f,0.f}};
  for (int kk = 0; kk < DDIM; kk += 16) {
    const int k = kk + lk;
    float4 a, b;
    if (k < LDIM) a = *reinterpret_cast<const float4*>(gw_real + (size_t)arow * LDIM + k);
    else          a = *reinterpret_cast<const float4*>(gw_imag + (size_t)arow * LDIM + (k - LDIM));
    b = *reinterpret_cast<const float4*>(codebook + (size_t)brow * DDIM + k);
    __syncthreads();
    As[lk+0][lm]=a.x; As[lk+1][lm]=a.y; As[lk+2][lm]=a.z; As[lk+3][lm]=a.w;
    Bs[lk+0][lm]=b.x; Bs[lk+1][lm]=b.y; Bs[lk+2][lm]=b.z; Bs[lk+3][lm]=b.w;
    __syncthreads();
#pragma unroll
    for (int k2 = 0; k2 < 16; ++k2) {
      const float4 a4 = *reinterpret_cast<const float4*>(&As[k2][ty << 2]);
      const float4 b4 = *reinterpret_cast<const float4*>(&Bs[k2][tx << 2]);
      const float av[4] = {a4.x, a4.y, a4.z, a4.w};
      const float bv[4] = {b4.x, b4.y, b4.z, b4.w};
#pragma unroll
      for (int i = 0; i < 4; ++i)
#pragma unroll
        for (int j = 0; j < 4; ++j)
          acc[i][j] = fmaf(av[i], bv[j], acc[i][j]);
    }
  }
  const float4 cn4 = *reinterpret_cast<const float4*>(cnorm + col0 + (tx << 2));
  const float cnv[4] = {cn4.x, cn4.y, cn4.z, cn4.w};
#pragma unroll
  for (int i = 0; i < 4; ++i) {
    const int rsub = (ty << 2) + i;
    const int row = row0 + rsub;
    const float zn = znorm[row];
    const int p = prevs[rsub];
    const float4 ad4 = *reinterpret_cast<const float4*>(adj + (size_t)p * NDIM + col0 + (tx << 2));
    const float adv[4] = {ad4.x, ad4.y, ad4.z, ad4.w};
    float bv = FLT_BIG;
    int bi = -1;
#pragma unroll
    for (int j = 0; j < 4; ++j) {
      const float bias = 0.8f * (1.0f / (1.0f + expf(-adv[j])));
      const float dv = (zn + cnv[j]) - 2.0f * acc[i][j] - bias;
      const int col = col0 + (tx << 2) + j;
      if (dv < bv) { bv = dv; bi = col; }
    }
    for (int m = 1; m < 16; m <<= 1) {
      const float ov = __shfl_xor(bv, m, 64);
      const int   oi = __shfl_xor(bi, m, 64);
      if (ov < bv || (ov == bv && oi < bi)) { bv = ov; bi = oi; }
    }
    if (tx == 0) {
      ws_min[(size_t)row * 128 + bn] = bv;
      ws_idx[(size_t)row * 128 + bn] = bi;
    }
  }
}

__global__ __launch_bounds__(128)
void argmin_reduce(const float* __restrict__ ws_min, const int* __restrict__ ws_idx,
                   float* __restrict__ out, float* __restrict__ minfinal,
                   int* __restrict__ idxfinal) {
  const int row = blockIdx.x;
  const int t = threadIdx.x;
  __shared__ float sv[128];
  __shared__ int   si[128];
  sv[t] = ws_min[(size_t)row * 128 + t];
  si[t] = ws_idx[(size_t)row * 128 + t];
  __syncthreads();
  for (int s = 64; s > 0; s >>= 1) {
    if (t < s) {
      const float ov = sv[t + s];
      const int   oi = si[t + s];
      if (ov < sv[t] || (ov == sv[t] && oi < si[t])) { sv[t] = ov; si[t] = oi; }
    }
    __syncthreads();
  }
  if (t == 0) {
    out[OFF_IDX + row] = (float)si[0];
    minfinal[row] = sv[0];
    idxfinal[row] = si[0];
  }
}

// ============ HOST ============

extern "C" void kernel_launch(void* const* d_in, const int* in_sizes, int n_in,
                              void* d_out, int out_size, void* d_ws, size_t ws_size,
                              hipStream_t stream) {
  const float* gw_real  = (const float*)d_in[0];
  const float* gw_imag  = (const float*)d_in[1];
  const int*   prev     = (const int*)d_in[2];
  const float* codebook = (const float*)d_in[3];
  const float* adj      = (const float*)d_in[4];
  const float* sal_w    = (const float*)d_in[5];
  const float* sal_b    = (const float*)d_in[6];
  const float* conf_w   = (const float*)d_in[7];
  const float* conf_b   = (const float*)d_in[8];
  float* out = (float*)d_out;
  char* ws = (char*)d_ws;

  const size_t matsz  = (size_t)RDIM * DDIM;             // elements per bf16 matrix
  const size_t tilesz = (size_t)RDIM * 128;              // per-64col-half top-2 arrays
  size_t need = 2 * matsz * 2                            // zh, ch (bf16)
              + 4 * tilesz * 4                           // wsv1,wsi1,wsv2,wsi2
              + (size_t)RDIM * MAXCAND * 4               // gcand
              + 6 * (size_t)RDIM * 4 + 4096;             // gcount,znorm,cnorm,minfinal,idxfinal,rowloss

  if (ws_size >= need) {
    unsigned short* zh = (unsigned short*)ws;
    unsigned short* chh = zh + matsz;
    float* wsv1 = (float*)(chh + matsz);
    int*   wsi1 = (int*)(wsv1 + tilesz);
    float* wsv2 = (float*)(wsi1 + tilesz);
    int*   wsi2 = (int*)(wsv2 + tilesz);
    int*   gcand  = (int*)(wsi2 + tilesz);
    int*   gcount = gcand + (size_t)RDIM * MAXCAND;
    float* znorm    = (float*)(gcount + RDIM);
    float* cnorm    = znorm + RDIM;
    float* minfinal = cnorm + NDIM;
    int*   idxfinal = (int*)(minfinal + RDIM);
    float* rowloss  = (float*)(idxfinal + RDIM);

    split_norms_kernel<<<RDIM + NDIM, 256, 0, stream>>>(gw_real, gw_imag, codebook,
                                                        zh, chh, znorm, cnorm);
    dist_mfma_kernel<<<dim3(64, 64), 256, 0, stream>>>(zh, chh, prev, adj,
                                                       znorm, cnorm, wsv1, wsi1, wsv2, wsi2);
    argmin_collect<<<RDIM, 64, 0, stream>>>(wsv1, wsi1, wsv2, wsi2,
                                            out, minfinal, idxfinal, gcount, gcand);
    refine_kernel<<<RDIM, 64, 0, stream>>>(gw_real, gw_imag, codebook, prev, adj,
                                           znorm, cnorm, gcount, gcand,
                                           out, minfinal, idxfinal);
    epilogue_kernel<<<RDIM, 256, 0, stream>>>(gw_real, gw_imag, codebook, sal_w, sal_b,
                                              conf_w, conf_b, minfinal, idxfinal, out, rowloss);
    loss_kernel<<<1, 256, 0, stream>>>(rowloss, out);
  } else {
    float* ws_min   = (float*)ws;
    int*   ws_idx   = (int*)(ws + (size_t)RDIM * 128 * 4);
    float* znorm    = (float*)(ws + (size_t)RDIM * 128 * 8);
    float* cnorm    = znorm + RDIM;
    float* minfinal = cnorm + NDIM;
    int*   idxfinal = (int*)(minfinal + RDIM);
    float* rowloss  = (float*)(idxfinal + RDIM);

    norms_kernel<<<RDIM + NDIM, 256, 0, stream>>>(gw_real, gw_imag, codebook, znorm, cnorm);
    dist_kernel<<<dim3(RDIM / 64, NDIM / 64), 256, 0, stream>>>(
        gw_real, gw_imag, codebook, prev, adj, znorm, cnorm, ws_min, ws_idx);
    argmin_reduce<<<RDIM, 128, 0, stream>>>(ws_min, ws_idx, out, minfinal, idxfinal);
    epilogue_kernel<<<RDIM, 256, 0, stream>>>(gw_real, gw_imag, codebook, sal_w, sal_b,
                                              conf_w, conf_b, minfinal, idxfinal, out, rowloss);
    loss_kernel<<<1, 256, 0, stream>>>(rowloss, out);
  }
}

// Round 5
// 253.329 us; speedup vs baseline: 8.6640x; 2.4896x over previous
//
#include <hip/hip_runtime.h>
#include <math.h>

#define RDIM 8192   // B*S
#define DDIM 1024   // 2*L
#define NDIM 8192
#define LDIM 512
#define NSTEPS 32   // K-steps of 32 over K=1024

#define OFF_REAL 0
#define OFF_IMAG 4194304
#define OFF_SAL  8388608
#define OFF_CONF 8396800
#define OFF_LOSS 8404992
#define OFF_IDX  8404993

#define MAXCAND 64
#define MARGIN_Q 76        // 1.1875 units of d: 0.8 bias range + bf16 pair err + quant
#define QSCALE 64.0f
#define FLT_BIG 3.4e38f

typedef __attribute__((ext_vector_type(8))) short bf16x8;
typedef __attribute__((ext_vector_type(8))) short short8v;
typedef __attribute__((ext_vector_type(4))) float f32x4;

__device__ __forceinline__ unsigned short f2bf(float x) {
  unsigned u = __builtin_bit_cast(unsigned, x);
  unsigned r = (u + 0x7fff + ((u >> 16) & 1)) >> 16;
  return (unsigned short)r;
}

__device__ __forceinline__ void load_lds16(const void* g, void* l) {
  __builtin_amdgcn_global_load_lds((const __attribute__((address_space(1))) void*)g,
                                   (__attribute__((address_space(3))) void*)l, 16, 0, 0);
}

// ============ bf16 cast + exact fp32 norms ============
__global__ __launch_bounds__(256)
void split_norms_kernel(const float* __restrict__ gw_real, const float* __restrict__ gw_imag,
                        const float* __restrict__ codebook,
                        unsigned short* __restrict__ zh, unsigned short* __restrict__ ch,
                        float* __restrict__ znorm, float* __restrict__ cnorm) {
  const int id = blockIdx.x;   // [0, 16384)
  const int t = threadIdx.x;   // 256
  float4 v;
  unsigned short* dst;
  if (id < RDIM) {
    v = (t < 128) ? reinterpret_cast<const float4*>(gw_real + (size_t)id * LDIM)[t]
                  : reinterpret_cast<const float4*>(gw_imag + (size_t)id * LDIM)[t - 128];
    dst = zh;
  } else {
    v = reinterpret_cast<const float4*>(codebook + (size_t)(id - RDIM) * DDIM)[t];
    dst = ch;
  }
  const size_t off = (size_t)(id < RDIM ? id : id - RDIM) * DDIM + t * 4;
  *reinterpret_cast<ushort4*>(dst + off) =
      make_ushort4(f2bf(v.x), f2bf(v.y), f2bf(v.z), f2bf(v.w));
  float s = v.x*v.x + v.y*v.y + v.z*v.z + v.w*v.w;
  __shared__ float red[256];
  red[t] = s;
  __syncthreads();
  for (int st = 128; st > 0; st >>= 1) {
    if (t < st) red[t] += red[t + st];
    __syncthreads();
  }
  if (t == 0) {
    if (id < RDIM) znorm[id] = red[0];
    else           cnorm[id - RDIM] = red[0];
  }
}

// ============ 128x128 bf16 GEMM, double-buffered, epilogue = quantized store ============
__global__ __launch_bounds__(256)
void dist_mfma_kernel(const unsigned short* __restrict__ zh, const unsigned short* __restrict__ ch,
                      const float* __restrict__ cnorm, short* __restrict__ q) {
  __shared__ unsigned short tA[2][4096];   // [128][32] swizzled, double-buffered
  __shared__ unsigned short tB[2][4096];

  const int bm = blockIdx.x, bn = blockIdx.y;
  const int row0 = bm * 128, col0 = bn * 128;
  const int tid = threadIdx.x;
  const int w = tid >> 6, l = tid & 63;
  const int wr = w >> 1, wc = w & 1;
  const int lr = l & 15, lg = l >> 4;

  // staging: physical chunk idx -> pre-swizzled global source chunk (rule #21, verified r2-r4)
  const int idx0 = w * 128 + l;
  const int idx1 = idx0 + 64;
  const int r0_ = idx0 >> 2, r1_ = idx1 >> 2;
  const int lc0 = (idx0 & 3) ^ ((r0_ >> 1) & 3);
  const int lc1 = (idx1 & 3) ^ ((r1_ >> 1) & 3);
  const size_t zo0 = (size_t)(row0 + r0_) * DDIM + lc0 * 8;
  const size_t zo1 = (size_t)(row0 + r1_) * DDIM + lc1 * 8;
  const size_t co0 = (size_t)(col0 + r0_) * DDIM + lc0 * 8;
  const size_t co1 = (size_t)(col0 + r1_) * DDIM + lc1 * 8;
  const int woff = w * 1024;

  const int swz = (lr >> 1) & 3;
  const int cpa = lg ^ swz;
  const int fragoff = lr * 32 + cpa * 8;

  f32x4 acc[4][4];
#pragma unroll
  for (int m = 0; m < 4; ++m)
#pragma unroll
    for (int n = 0; n < 4; ++n)
      acc[m][n] = (f32x4){0.f, 0.f, 0.f, 0.f};

  // prologue: stage K-step 0 into buffer 0
  load_lds16(zh + zo0, &tA[0][woff]);
  load_lds16(zh + zo1, &tA[0][woff + 512]);
  load_lds16(ch + co0, &tB[0][woff]);
  load_lds16(ch + co1, &tB[0][woff + 512]);
  __syncthreads();

  for (int t = 0; t < NSTEPS; ++t) {
    const int cur = t & 1;
    if (t + 1 < NSTEPS) {               // issue next-tile loads BEFORE compute (T3)
      const int nxt = cur ^ 1;
      const int k = (t + 1) * 32;
      load_lds16(zh + zo0 + k, &tA[nxt][woff]);
      load_lds16(zh + zo1 + k, &tA[nxt][woff + 512]);
      load_lds16(ch + co0 + k, &tB[nxt][woff]);
      load_lds16(ch + co1 + k, &tB[nxt][woff + 512]);
    }
    bf16x8 bfr[4];
#pragma unroll
    for (int n = 0; n < 4; ++n)
      bfr[n] = *reinterpret_cast<const bf16x8*>(&tB[cur][(wc * 64 + n * 16) * 32 + fragoff]);
#pragma unroll
    for (int m = 0; m < 4; ++m) {
      const bf16x8 afr = *reinterpret_cast<const bf16x8*>(&tA[cur][(wr * 64 + m * 16) * 32 + fragoff]);
#pragma unroll
      for (int n = 0; n < 4; ++n)
        acc[m][n] = __builtin_amdgcn_mfma_f32_16x16x32_bf16(afr, bfr[n], acc[m][n], 0, 0, 0);
    }
    __syncthreads();   // drains stage(t+1) loads + protects buffer reuse
  }

  // epilogue: s = cn - 2*dot, quantize to int16 (scale 64), store
  float cn[4];
#pragma unroll
  for (int n = 0; n < 4; ++n) cn[n] = cnorm[col0 + wc * 64 + n * 16 + lr];

#pragma unroll
  for (int m = 0; m < 4; ++m) {
#pragma unroll
    for (int reg = 0; reg < 4; ++reg) {
      const int row = row0 + wr * 64 + m * 16 + lg * 4 + reg;
#pragma unroll
      for (int n = 0; n < 4; ++n) {
        const float s = cn[n] - 2.0f * acc[m][n][reg];
        int qi = __float2int_rn(s * QSCALE);
        qi = qi > 32767 ? 32767 : (qi < -32767 ? -32767 : qi);
        q[(size_t)row * NDIM + col0 + wc * 64 + n * 16 + lr] = (short)qi;
      }
    }
  }
}

// ============ streaming per-row min + candidate collection ============
__global__ __launch_bounds__(256)
void collect_kernel(const short* __restrict__ q, const int* __restrict__ prev,
                    const float* __restrict__ adj, const float* __restrict__ znorm,
                    float* __restrict__ out, float* __restrict__ minfinal,
                    int* __restrict__ idxfinal,
                    int* __restrict__ gcount, int* __restrict__ gcand) {
  __shared__ unsigned s_wmin[4];
  __shared__ int s_cnt;
  __shared__ int s_list[MAXCAND];
  const int row = blockIdx.x;
  const int t = threadIdx.x;    // 256
  if (t == 0) s_cnt = 0;
  short8v v[4];
  unsigned kmin = 0xffffffffu;
#pragma unroll
  for (int c = 0; c < 4; ++c) {
    v[c] = *reinterpret_cast<const short8v*>(q + (size_t)row * NDIM + (c * 256 + t) * 8);
#pragma unroll
    for (int j = 0; j < 8; ++j) {
      const int col = (c * 256 + t) * 8 + j;
      const unsigned key = (((unsigned)((int)v[c][j] + 32768)) << 13) | (unsigned)col;
      kmin = (key < kmin) ? key : kmin;     // lex (q, col) min
    }
  }
  for (int m = 1; m < 64; m <<= 1) {
    const unsigned o = (unsigned)__shfl_xor((int)kmin, m, 64);
    kmin = (o < kmin) ? o : kmin;
  }
  if ((t & 63) == 0) s_wmin[t >> 6] = kmin;
  __syncthreads();
  unsigned gk = s_wmin[0];
  gk = gk < s_wmin[1] ? gk : s_wmin[1];
  gk = gk < s_wmin[2] ? gk : s_wmin[2];
  gk = gk < s_wmin[3] ? gk : s_wmin[3];
  const int qmin = (int)(gk >> 13) - 32768;
  const int winner = (int)(gk & 8191u);
  const int thr = qmin + MARGIN_Q;
#pragma unroll
  for (int c = 0; c < 4; ++c) {
#pragma unroll
    for (int j = 0; j < 8; ++j) {
      if ((int)v[c][j] <= thr) {
        const int pos = atomicAdd(&s_cnt, 1);
        if (pos < MAXCAND) s_list[pos] = (c * 256 + t) * 8 + j;
      }
    }
  }
  __syncthreads();
  const int cnt = (s_cnt < MAXCAND) ? s_cnt : MAXCAND;
  if (t == 0) {
    gcount[row] = (cnt <= 1) ? 1 : cnt;
    out[OFF_IDX + row] = (float)winner;
    idxfinal[row] = winner;
    if (cnt <= 1) {
      const int p = prev[row];
      const float bias = 0.8f / (1.0f + expf(-adj[(size_t)p * NDIM + winner]));
      minfinal[row] = znorm[row] + (float)qmin * (1.0f / QSCALE) - bias;
    } else {
      minfinal[row] = znorm[row] + (float)qmin * (1.0f / QSCALE);  // placeholder; refine overwrites
    }
  }
  if (cnt > 1 && t < cnt) gcand[(size_t)row * MAXCAND + t] = s_list[t];
}

// ============ exact fp32 refine of ambiguous rows (biased lex-min over candidates) ============
__global__ __launch_bounds__(64)
void refine_kernel(const float* __restrict__ gw_real, const float* __restrict__ gw_imag,
                   const float* __restrict__ codebook, const int* __restrict__ prev,
                   const float* __restrict__ adj, const float* __restrict__ znorm,
                   const float* __restrict__ cnorm,
                   const int* __restrict__ gcount, const int* __restrict__ gcand,
                   float* __restrict__ out, float* __restrict__ minfinal,
                   int* __restrict__ idxfinal) {
  const int row = blockIdx.x;
  const int t = threadIdx.x;   // 64 lanes, 16 contiguous floats each
  const int K = gcount[row];
  if (K <= 1) return;
  const int base = t * 16;
  const float* zp = (base < LDIM) ? gw_real + (size_t)row * LDIM + base
                                  : gw_imag + (size_t)row * LDIM + (base - LDIM);
  float z[16];
#pragma unroll
  for (int c = 0; c < 4; ++c) {
    const float4 v = reinterpret_cast<const float4*>(zp)[c];
    z[c*4+0] = v.x; z[c*4+1] = v.y; z[c*4+2] = v.z; z[c*4+3] = v.w;
  }
  const float zn = znorm[row];
  const int p = prev[row];
  float bestd = FLT_BIG;
  int besti = 0x7fffffff;
  for (int j = 0; j < K; ++j) {
    const int idx = gcand[(size_t)row * MAXCAND + j];
    const float* cp = codebook + (size_t)idx * DDIM + base;
    float dot = 0.f;
#pragma unroll
    for (int c = 0; c < 4; ++c) {
      const float4 v = reinterpret_cast<const float4*>(cp)[c];
      dot += z[c*4+0]*v.x + z[c*4+1]*v.y + z[c*4+2]*v.z + z[c*4+3]*v.w;
    }
    for (int m = 1; m < 64; m <<= 1) dot += __shfl_xor(dot, m, 64);
    const float d = zn + cnorm[idx] - 2.0f * dot
                  - 0.8f / (1.0f + expf(-adj[(size_t)p * NDIM + idx]));
    if (d < bestd || (d == bestd && idx < besti)) { bestd = d; besti = idx; }
  }
  if (t == 0) {
    out[OFF_IDX + row] = (float)besti;
    minfinal[row] = bestd;
    idxfinal[row] = besti;
  }
}

// ============ SHARED EPILOGUE ============

__global__ __launch_bounds__(256)
void epilogue_kernel(const float* __restrict__ gw_real, const float* __restrict__ gw_imag,
                     const float* __restrict__ codebook,
                     const float* __restrict__ sal_w, const float* __restrict__ sal_b,
                     const float* __restrict__ conf_w, const float* __restrict__ conf_b,
                     const float* __restrict__ minfinal, const int* __restrict__ idxfinal,
                     float* __restrict__ out, float* __restrict__ rowloss) {
  const int row = blockIdx.x;
  const int t = threadIdx.x;
  const int k = t << 2;
  const int idx = idxfinal[row];
  const float4 qv = *reinterpret_cast<const float4*>(codebook + (size_t)idx * DDIM + k);
  float4 z;
  if (k < LDIM) z = *reinterpret_cast<const float4*>(gw_real + (size_t)row * LDIM + k);
  else          z = *reinterpret_cast<const float4*>(gw_imag + (size_t)row * LDIM + (k - LDIM));
  const float dx = qv.x - z.x, dy = qv.y - z.y, dz = qv.z - z.z, dw = qv.w - z.w;
  float4 st;
  st.x = z.x + dx; st.y = z.y + dy; st.z = z.z + dz; st.w = z.w + dw;
  float* dst = (k < LDIM) ? (out + OFF_REAL + (size_t)row * LDIM + k)
                          : (out + OFF_IMAG + (size_t)row * LDIM + (k - LDIM));
  *reinterpret_cast<float4*>(dst) = st;
  const float4 sw = *reinterpret_cast<const float4*>(sal_w + k);
  const float4 cw = *reinterpret_cast<const float4*>(conf_w + k);
  const float sdot = st.x*sw.x + st.y*sw.y + st.z*sw.z + st.w*sw.w;
  const float cdot = st.x*cw.x + st.y*cw.y + st.z*cw.z + st.w*cw.w;
  const float dif = dx*dx + dy*dy + dz*dz + dw*dw;
  __shared__ float r1[256], r2[256], r3[256];
  r1[t] = sdot; r2[t] = cdot; r3[t] = dif;
  __syncthreads();
  for (int s = 128; s > 0; s >>= 1) {
    if (t < s) { r1[t] += r1[t + s]; r2[t] += r2[t + s]; r3[t] += r3[t + s]; }
    __syncthreads();
  }
  if (t == 0) {
    out[OFF_SAL + row]  = r1[0] + sal_b[0] + 0.1f * (-minfinal[row]);
    out[OFF_CONF + row] = 1.0f / (1.0f + expf(-(r2[0] + conf_b[0])));
    rowloss[row] = r3[0];
  }
}

__global__ __launch_bounds__(256)
void loss_kernel(const float* __restrict__ rowloss, float* __restrict__ out) {
  const int t = threadIdx.x;
  float s = 0.f;
  for (int i = t; i < RDIM; i += 256) s += rowloss[i];
  __shared__ float red[256];
  red[t] = s;
  __syncthreads();
  for (int st = 128; st > 0; st >>= 1) {
    if (t < st) red[t] += red[t + st];
    __syncthreads();
  }
  if (t == 0) {
    const float m = red[0] / (float)((size_t)RDIM * DDIM);
    out[OFF_LOSS] = m + 0.01f * m;
  }
}

// ============ FALLBACK (round-1 fp32 path) ============

__global__ __launch_bounds__(256)
void norms_kernel(const float* __restrict__ gw_real, const float* __restrict__ gw_imag,
                  const float* __restrict__ codebook,
                  float* __restrict__ znorm, float* __restrict__ cnorm) {
  const int id = blockIdx.x;
  const int t = threadIdx.x;
  float s;
  if (id < RDIM) {
    const float4* zr = reinterpret_cast<const float4*>(gw_real + (size_t)id * LDIM);
    const float4* zi = reinterpret_cast<const float4*>(gw_imag + (size_t)id * LDIM);
    const float4 v = (t < 128) ? zr[t] : zi[t - 128];
    s = v.x*v.x + v.y*v.y + v.z*v.z + v.w*v.w;
  } else {
    const float4* c = reinterpret_cast<const float4*>(codebook + (size_t)(id - RDIM) * DDIM);
    const float4 v = c[t];
    s = v.x*v.x + v.y*v.y + v.z*v.z + v.w*v.w;
  }
  __shared__ float red[256];
  red[t] = s;
  __syncthreads();
  for (int st = 128; st > 0; st >>= 1) {
    if (t < st) red[t] += red[t + st];
    __syncthreads();
  }
  if (t == 0) {
    if (id < RDIM) znorm[id] = red[0];
    else           cnorm[id - RDIM] = red[0];
  }
}

__global__ __launch_bounds__(256)
void dist_kernel(const float* __restrict__ gw_real, const float* __restrict__ gw_imag,
                 const float* __restrict__ codebook, const int* __restrict__ prev,
                 const float* __restrict__ adj, const float* __restrict__ znorm,
                 const float* __restrict__ cnorm,
                 float* __restrict__ ws_min, int* __restrict__ ws_idx) {
  __shared__ float As[16][64];
  __shared__ float Bs[16][64];
  __shared__ int prevs[64];
  const int bm = blockIdx.x, bn = blockIdx.y;
  const int row0 = bm * 64, col0 = bn * 64;
  const int tid = threadIdx.x;
  const int tx = tid & 15, ty = tid >> 4;
  if (tid < 64) prevs[tid] = prev[row0 + tid];
  const int lm = tid >> 2;
  const int lk = (tid & 3) << 2;
  const int arow = row0 + lm;
  const int brow = col0 + lm;
  float acc[4][4] = {{0.f,0.f,0.f,0.f},{0.f,0.f,0.f,0.f},{0.f,0.f,0.f,0.f},{0.f,0.f,0.f,0.f}};
  for (int kk = 0; kk < DDIM; kk += 16) {
    const int k = kk + lk;
    float4 a, b;
    if (k < LDIM) a = *reinterpret_cast<const float4*>(gw_real + (size_t)arow * LDIM + k);
    else          a = *reinterpret_cast<const float4*>(gw_imag + (size_t)arow * LDIM + (k - LDIM));
    b = *reinterpret_cast<const float4*>(codebook + (size_t)brow * DDIM + k);
    __syncthreads();
    As[lk+0][lm]=a.x; As[lk+1][lm]=a.y; As[lk+2][lm]=a.z; As[lk+3][lm]=a.w;
    Bs[lk+0][lm]=b.x; Bs[lk+1][lm]=b.y; Bs[lk+2][lm]=b.z; Bs[lk+3][lm]=b.w;
    __syncthreads();
#pragma unroll
    for (int k2 = 0; k2 < 16; ++k2) {
      const float4 a4 = *reinterpret_cast<const float4*>(&As[k2][ty << 2]);
      const float4 b4 = *reinterpret_cast<const float4*>(&Bs[k2][tx << 2]);
      const float av[4] = {a4.x, a4.y, a4.z, a4.w};
      const float bv[4] = {b4.x, b4.y, b4.z, b4.w};
#pragma unroll
      for (int i = 0; i < 4; ++i)
#pragma unroll
        for (int j = 0; j < 4; ++j)
          acc[i][j] = fmaf(av[i], bv[j], acc[i][j]);
    }
  }
  const float4 cn4 = *reinterpret_cast<const float4*>(cnorm + col0 + (tx << 2));
  const float cnv[4] = {cn4.x, cn4.y, cn4.z, cn4.w};
#pragma unroll
  for (int i = 0; i < 4; ++i) {
    const int rsub = (ty << 2) + i;
    const int row = row0 + rsub;
    const float zn = znorm[row];
    const int p = prevs[rsub];
    const float4 ad4 = *reinterpret_cast<const float4*>(adj + (size_t)p * NDIM + col0 + (tx << 2));
    const float adv[4] = {ad4.x, ad4.y, ad4.z, ad4.w};
    float bv = FLT_BIG;
    int bi = -1;
#pragma unroll
    for (int j = 0; j < 4; ++j) {
      const float bias = 0.8f * (1.0f / (1.0f + expf(-adv[j])));
      const float dv = (zn + cnv[j]) - 2.0f * acc[i][j] - bias;
      const int col = col0 + (tx << 2) + j;
      if (dv < bv) { bv = dv; bi = col; }
    }
    for (int m = 1; m < 16; m <<= 1) {
      const float ov = __shfl_xor(bv, m, 64);
      const int   oi = __shfl_xor(bi, m, 64);
      if (ov < bv || (ov == bv && oi < bi)) { bv = ov; bi = oi; }
    }
    if (tx == 0) {
      ws_min[(size_t)row * 128 + bn] = bv;
      ws_idx[(size_t)row * 128 + bn] = bi;
    }
  }
}

__global__ __launch_bounds__(128)
void argmin_reduce(const float* __restrict__ ws_min, const int* __restrict__ ws_idx,
                   float* __restrict__ out, float* __restrict__ minfinal,
                   int* __restrict__ idxfinal) {
  const int row = blockIdx.x;
  const int t = threadIdx.x;
  __shared__ float sv[128];
  __shared__ int   si[128];
  sv[t] = ws_min[(size_t)row * 128 + t];
  si[t] = ws_idx[(size_t)row * 128 + t];
  __syncthreads();
  for (int s = 64; s > 0; s >>= 1) {
    if (t < s) {
      const float ov = sv[t + s];
      const int   oi = si[t + s];
      if (ov < sv[t] || (ov == sv[t] && oi < si[t])) { sv[t] = ov; si[t] = oi; }
    }
    __syncthreads();
  }
  if (t == 0) {
    out[OFF_IDX + row] = (float)si[0];
    minfinal[row] = sv[0];
    idxfinal[row] = si[0];
  }
}

// ============ HOST ============

extern "C" void kernel_launch(void* const* d_in, const int* in_sizes, int n_in,
                              void* d_out, int out_size, void* d_ws, size_t ws_size,
                              hipStream_t stream) {
  const float* gw_real  = (const float*)d_in[0];
  const float* gw_imag  = (const float*)d_in[1];
  const int*   prev     = (const int*)d_in[2];
  const float* codebook = (const float*)d_in[3];
  const float* adj      = (const float*)d_in[4];
  const float* sal_w    = (const float*)d_in[5];
  const float* sal_b    = (const float*)d_in[6];
  const float* conf_w   = (const float*)d_in[7];
  const float* conf_b   = (const float*)d_in[8];
  float* out = (float*)d_out;
  char* ws = (char*)d_ws;

  const size_t matsz = (size_t)RDIM * DDIM;              // bf16 elements per matrix
  const size_t qsz   = (size_t)RDIM * NDIM;              // int16 score matrix
  size_t need = 2 * matsz * 2                            // zh, ch (bf16)
              + qsz * 2                                  // q (int16)
              + (size_t)RDIM * MAXCAND * 4               // gcand
              + 6 * (size_t)RDIM * 4 + 4096;             // gcount,znorm,cnorm,minfinal,idxfinal,rowloss

  if (ws_size >= need) {
    unsigned short* zh = (unsigned short*)ws;
    unsigned short* chh = zh + matsz;
    short* q = (short*)(chh + matsz);
    int*   gcand  = (int*)(q + qsz);
    int*   gcount = gcand + (size_t)RDIM * MAXCAND;
    float* znorm    = (float*)(gcount + RDIM);
    float* cnorm    = znorm + RDIM;
    float* minfinal = cnorm + NDIM;
    int*   idxfinal = (int*)(minfinal + RDIM);
    float* rowloss  = (float*)(idxfinal + RDIM);

    split_norms_kernel<<<RDIM + NDIM, 256, 0, stream>>>(gw_real, gw_imag, codebook,
                                                        zh, chh, znorm, cnorm);
    dist_mfma_kernel<<<dim3(64, 64), 256, 0, stream>>>(zh, chh, cnorm, q);
    collect_kernel<<<RDIM, 256, 0, stream>>>(q, prev, adj, znorm,
                                             out, minfinal, idxfinal, gcount, gcand);
    refine_kernel<<<RDIM, 64, 0, stream>>>(gw_real, gw_imag, codebook, prev, adj,
                                           znorm, cnorm, gcount, gcand,
                                           out, minfinal, idxfinal);
    epilogue_kernel<<<RDIM, 256, 0, stream>>>(gw_real, gw_imag, codebook, sal_w, sal_b,
                                              conf_w, conf_b, minfinal, idxfinal, out, rowloss);
    loss_kernel<<<1, 256, 0, stream>>>(rowloss, out);
  } else {
    float* ws_min   = (float*)ws;
    int*   ws_idx   = (int*)(ws + (size_t)RDIM * 128 * 4);
    float* znorm    = (float*)(ws + (size_t)RDIM * 128 * 8);
    float* cnorm    = znorm + RDIM;
    float* minfinal = cnorm + NDIM;
    int*   idxfinal = (int*)(minfinal + RDIM);
    float* rowloss  = (float*)(idxfinal + RDIM);

    norms_kernel<<<RDIM + NDIM, 256, 0, stream>>>(gw_real, gw_imag, codebook, znorm, cnorm);
    dist_kernel<<<dim3(RDIM / 64, NDIM / 64), 256, 0, stream>>>(
        gw_real, gw_imag, codebook, prev, adj, znorm, cnorm, ws_min, ws_idx);
    argmin_reduce<<<RDIM, 128, 0, stream>>>(ws_min, ws_idx, out, minfinal, idxfinal);
    epilogue_kernel<<<RDIM, 256, 0, stream>>>(gw_real, gw_imag, codebook, sal_w, sal_b,
                                              conf_w, conf_b, minfinal, idxfinal, out, rowloss);
    loss_kernel<<<1, 256, 0, stream>>>(rowloss, out);
  }
}

// Round 6
// 230.065 us; speedup vs baseline: 9.5401x; 1.1011x over previous
//
#include <hip/hip_runtime.h>
#include <math.h>

#define RDIM 8192   // B*S
#define DDIM 1024   // 2*L
#define NDIM 8192
#define LDIM 512
#define KT 16       // K-tiles of 64 over K=1024

#define OFF_REAL 0
#define OFF_IMAG 4194304
#define OFF_SAL  8388608
#define OFF_CONF 8396800
#define OFF_LOSS 8404992
#define OFF_IDX  8404993

#define MAXCAND 64
#define MARGIN_Q 76        // 1.1875 units of d: 0.8 bias range + bf16 pair err + quant
#define QSCALE 64.0f
#define FLT_BIG 3.4e38f

typedef __attribute__((ext_vector_type(8))) short bf16x8;
typedef __attribute__((ext_vector_type(8))) short short8v;
typedef __attribute__((ext_vector_type(4))) float f32x4;

__device__ __forceinline__ unsigned short f2bf(float x) {
  unsigned u = __builtin_bit_cast(unsigned, x);
  unsigned r = (u + 0x7fff + ((u >> 16) & 1)) >> 16;
  return (unsigned short)r;
}

__device__ __forceinline__ void load_lds16(const void* g, void* l) {
  __builtin_amdgcn_global_load_lds((const __attribute__((address_space(1))) void*)g,
                                   (__attribute__((address_space(3))) void*)l, 16, 0, 0);
}

__device__ __forceinline__ short clampq(float s) {
  int qi = __float2int_rn(s * QSCALE);
  qi = qi > 32767 ? 32767 : (qi < -32767 ? -32767 : qi);
  return (short)qi;
}

// ============ bf16 cast + exact fp32 norms ============
__global__ __launch_bounds__(256)
void split_norms_kernel(const float* __restrict__ gw_real, const float* __restrict__ gw_imag,
                        const float* __restrict__ codebook,
                        unsigned short* __restrict__ zh, unsigned short* __restrict__ ch,
                        float* __restrict__ znorm, float* __restrict__ cnorm) {
  const int id = blockIdx.x;   // [0, 16384)
  const int t = threadIdx.x;   // 256
  float4 v;
  unsigned short* dst;
  if (id < RDIM) {
    v = (t < 128) ? reinterpret_cast<const float4*>(gw_real + (size_t)id * LDIM)[t]
                  : reinterpret_cast<const float4*>(gw_imag + (size_t)id * LDIM)[t - 128];
    dst = zh;
  } else {
    v = reinterpret_cast<const float4*>(codebook + (size_t)(id - RDIM) * DDIM)[t];
    dst = ch;
  }
  const size_t off = (size_t)(id < RDIM ? id : id - RDIM) * DDIM + t * 4;
  *reinterpret_cast<ushort4*>(dst + off) =
      make_ushort4(f2bf(v.x), f2bf(v.y), f2bf(v.z), f2bf(v.w));
  float s = v.x*v.x + v.y*v.y + v.z*v.z + v.w*v.w;
  __shared__ float red[256];
  red[t] = s;
  __syncthreads();
  for (int st = 128; st > 0; st >>= 1) {
    if (t < st) red[t] += red[t + st];
    __syncthreads();
  }
  if (t == 0) {
    if (id < RDIM) znorm[id] = red[0];
    else           cnorm[id - RDIM] = red[0];
  }
}

// ============ 256x256 tile, BK=64, 8-wave 8-phase bf16 GEMM -> quantized int16 scores ============
// Swapped operands: acc[mf][nf][reg] = dot(c-row(col0+wn*64+mf*16+lg*4+reg),
//                                          z-row(row0+wm*128+nf*16+lr))
#define STAGE(basep, kt, ldsbyte) do {                                        \
    load_lds16((basep) + eo1 + (kt) * 64, L + (ldsbyte) + wid * 1024);        \
    load_lds16((basep) + eo2 + (kt) * 64, L + (ldsbyte) + 8192 + wid * 1024); \
  } while (0)

__global__ __launch_bounds__(512)
void dist_mfma_kernel(const unsigned short* __restrict__ zh, const unsigned short* __restrict__ ch,
                      const float* __restrict__ cnorm, short* __restrict__ q) {
  __shared__ unsigned short ldsbuf[65536];   // 128 KB: [buf][A 32K | B 32K]
  char* const L = (char*)ldsbuf;

  // XCD-aware swizzle (1024 blocks = 8 XCDs x 128, bijective)
  const int sidx = (int)blockIdx.x;
  const int sw = (sidx & 7) * 128 + (sidx >> 3);
  const int bm = sw >> 5, bn = sw & 31;
  const int row0 = bm * 256, col0 = bn * 256;

  const int tid = threadIdx.x;
  const int wid = tid >> 6, l = tid & 63;
  const int wm = wid >> 2, wn = wid & 3;       // 2 x 4 wave grid
  const int lr = l & 15, lg = l >> 4;

  // ---- staging geometry: half-tile = 128 rows x 64 cols bf16 = 1024 chunks of 16B
  // physical chunk p -> row r = p>>3, phys chunk cp = p&7, logical chunk c = cp ^ (r&7)
  const int p1 = tid, p2 = tid + 512;
  const int r1 = p1 >> 3, c1 = (p1 & 7) ^ (r1 & 7);
  const int r2 = p2 >> 3, c2 = (p2 & 7) ^ (r2 & 7);
  const int eo1 = r1 * DDIM + c1 * 8;   // element offset within half (global row len 1024)
  const int eo2 = r2 * DDIM + c2 * 8;
  const unsigned short* const az0 = zh + (size_t)row0 * DDIM;
  const unsigned short* const az1 = zh + (size_t)(row0 + 128) * DDIM;
  const unsigned short* const ac0 = ch + (size_t)col0 * DDIM;
  const unsigned short* const ac1 = ch + (size_t)(col0 + 128) * DDIM;

  // ---- fragment read offsets (row = base + lr, chunk' = (kh*4+lg) ^ (lr&7))
  const int fo0 = lr * 128 + ((lg ^ (lr & 7)) << 4);
  const int fo1 = fo0 ^ 64;

  f32x4 acc[4][8];
#pragma unroll
  for (int i = 0; i < 4; ++i)
#pragma unroll
    for (int j = 0; j < 8; ++j)
      acc[i][j] = (f32x4){0.f, 0.f, 0.f, 0.f};

  bf16x8 cfA[2][2], cfB[2][2], zf[4][2];

  // ---- prologue: tile0 (A+B) into buf0, B(1) into buf1; A(1) comes from loop t=0
  STAGE(az0, 0, 0);
  STAGE(az1, 0, 16384);
  STAGE(ac0, 0, 32768);
  STAGE(ac1, 0, 49152);
  STAGE(ac0, 1, 98304);
  STAGE(ac1, 1, 114688);
  asm volatile("s_waitcnt vmcnt(4)" ::: "memory");   // tile0 landed; B(1) may fly
  __builtin_amdgcn_sched_barrier(0);
  __builtin_amdgcn_s_barrier();

  for (int t = 0; t < KT; ++t) {
    const int buf = t & 1, nbuf = buf ^ 1;
    const char* const Ab = L + buf * 65536 + wm * 16384;          // wave's z-half
    const char* const Bb = L + buf * 65536 + 32768 + wn * 8192;   // wave's c-64-block

    // ======== P1: quadrant (mf 0-1, nf 0-3); stage A0(t+1) ========
#pragma unroll
    for (int i = 0; i < 2; ++i) {
      cfA[i][0] = *reinterpret_cast<const bf16x8*>(Bb + i * 2048 + fo0);
      cfA[i][1] = *reinterpret_cast<const bf16x8*>(Bb + i * 2048 + fo1);
    }
#pragma unroll
    for (int j = 0; j < 4; ++j) {
      zf[j][0] = *reinterpret_cast<const bf16x8*>(Ab + j * 2048 + fo0);
      zf[j][1] = *reinterpret_cast<const bf16x8*>(Ab + j * 2048 + fo1);
    }
    if (t + 1 < KT) STAGE(az0, t + 1, nbuf * 65536);
    __builtin_amdgcn_sched_barrier(0);
    __builtin_amdgcn_s_barrier();
    __builtin_amdgcn_s_setprio(1);
#pragma unroll
    for (int kh = 0; kh < 2; ++kh)
#pragma unroll
      for (int i = 0; i < 2; ++i)
#pragma unroll
        for (int j = 0; j < 4; ++j)
          acc[i][j] = __builtin_amdgcn_mfma_f32_16x16x32_bf16(cfA[i][kh], zf[j][kh], acc[i][j], 0, 0, 0);
    __builtin_amdgcn_s_setprio(0);
    __builtin_amdgcn_sched_barrier(0);
    __builtin_amdgcn_s_barrier();

    // ======== P2: quadrant (mf 2-3, nf 0-3); stage A1(t+1) ========
#pragma unroll
    for (int i = 0; i < 2; ++i) {
      cfB[i][0] = *reinterpret_cast<const bf16x8*>(Bb + (2 + i) * 2048 + fo0);
      cfB[i][1] = *reinterpret_cast<const bf16x8*>(Bb + (2 + i) * 2048 + fo1);
    }
    if (t + 1 < KT) STAGE(az1, t + 1, nbuf * 65536 + 16384);
    __builtin_amdgcn_sched_barrier(0);
    __builtin_amdgcn_s_barrier();
    __builtin_amdgcn_s_setprio(1);
#pragma unroll
    for (int kh = 0; kh < 2; ++kh)
#pragma unroll
      for (int i = 0; i < 2; ++i)
#pragma unroll
        for (int j = 0; j < 4; ++j)
          acc[2 + i][j] = __builtin_amdgcn_mfma_f32_16x16x32_bf16(cfB[i][kh], zf[j][kh], acc[2 + i][j], 0, 0, 0);
    __builtin_amdgcn_s_setprio(0);
    __builtin_amdgcn_sched_barrier(0);
    __builtin_amdgcn_s_barrier();

    // ======== P3: quadrant (mf 2-3, nf 4-7); stage B0(t+2) into current buf ========
#pragma unroll
    for (int j = 0; j < 4; ++j) {
      zf[j][0] = *reinterpret_cast<const bf16x8*>(Ab + (4 + j) * 2048 + fo0);
      zf[j][1] = *reinterpret_cast<const bf16x8*>(Ab + (4 + j) * 2048 + fo1);
    }
    if (t + 2 < KT) STAGE(ac0, t + 2, buf * 65536 + 32768);
    __builtin_amdgcn_sched_barrier(0);
    __builtin_amdgcn_s_barrier();
    __builtin_amdgcn_s_setprio(1);
#pragma unroll
    for (int kh = 0; kh < 2; ++kh)
#pragma unroll
      for (int i = 0; i < 2; ++i)
#pragma unroll
        for (int j = 0; j < 4; ++j)
          acc[2 + i][4 + j] = __builtin_amdgcn_mfma_f32_16x16x32_bf16(cfB[i][kh], zf[j][kh], acc[2 + i][4 + j], 0, 0, 0);
    __builtin_amdgcn_s_setprio(0);
    __builtin_amdgcn_sched_barrier(0);
    __builtin_amdgcn_s_barrier();

    // ======== P4: quadrant (mf 0-1, nf 4-7); stage B1(t+2); counted vmcnt ========
    if (t + 2 < KT) STAGE(ac1, t + 2, buf * 65536 + 49152);
    if (t < KT - 2) { asm volatile("s_waitcnt vmcnt(4)" ::: "memory"); }
    else            { asm volatile("s_waitcnt vmcnt(0)" ::: "memory"); }
    __builtin_amdgcn_sched_barrier(0);
    __builtin_amdgcn_s_barrier();
    __builtin_amdgcn_s_setprio(1);
#pragma unroll
    for (int kh = 0; kh < 2; ++kh)
#pragma unroll
      for (int i = 0; i < 2; ++i)
#pragma unroll
        for (int j = 0; j < 4; ++j)
          acc[i][4 + j] = __builtin_amdgcn_mfma_f32_16x16x32_bf16(cfA[i][kh], zf[j][kh], acc[i][4 + j], 0, 0, 0);
    __builtin_amdgcn_s_setprio(0);
    __builtin_amdgcn_sched_barrier(0);
    __builtin_amdgcn_s_barrier();
  }

  // ---- epilogue: s = cn - 2*dot, quantize, short4 stores
  const int czero = col0 + wn * 64;
  const int zzero = row0 + wm * 128;
#pragma unroll
  for (int i = 0; i < 4; ++i) {
    const int cc = czero + i * 16 + lg * 4;
    const float4 cn4 = *reinterpret_cast<const float4*>(cnorm + cc);
#pragma unroll
    for (int j = 0; j < 8; ++j) {
      const int zr = zzero + j * 16 + lr;
      const f32x4 a = acc[i][j];
      *reinterpret_cast<short4*>(q + (size_t)zr * NDIM + cc) =
          make_short4(clampq(cn4.x - 2.0f * a[0]), clampq(cn4.y - 2.0f * a[1]),
                      clampq(cn4.z - 2.0f * a[2]), clampq(cn4.w - 2.0f * a[3]));
    }
  }
}

// ============ streaming per-row min + candidate collection ============
__global__ __launch_bounds__(256)
void collect_kernel(const short* __restrict__ q, const int* __restrict__ prev,
                    const float* __restrict__ adj, const float* __restrict__ znorm,
                    float* __restrict__ out, float* __restrict__ minfinal,
                    int* __restrict__ idxfinal,
                    int* __restrict__ gcount, int* __restrict__ gcand) {
  __shared__ unsigned s_wmin[4];
  __shared__ int s_cnt;
  __shared__ int s_list[MAXCAND];
  const int row = blockIdx.x;
  const int t = threadIdx.x;    // 256
  if (t == 0) s_cnt = 0;
  short8v v[4];
  unsigned kmin = 0xffffffffu;
#pragma unroll
  for (int c = 0; c < 4; ++c) {
    v[c] = *reinterpret_cast<const short8v*>(q + (size_t)row * NDIM + (c * 256 + t) * 8);
#pragma unroll
    for (int j = 0; j < 8; ++j) {
      const int col = (c * 256 + t) * 8 + j;
      const unsigned key = (((unsigned)((int)v[c][j] + 32768)) << 13) | (unsigned)col;
      kmin = (key < kmin) ? key : kmin;     // lex (q, col) min
    }
  }
  for (int m = 1; m < 64; m <<= 1) {
    const unsigned o = (unsigned)__shfl_xor((int)kmin, m, 64);
    kmin = (o < kmin) ? o : kmin;
  }
  if ((t & 63) == 0) s_wmin[t >> 6] = kmin;
  __syncthreads();
  unsigned gk = s_wmin[0];
  gk = gk < s_wmin[1] ? gk : s_wmin[1];
  gk = gk < s_wmin[2] ? gk : s_wmin[2];
  gk = gk < s_wmin[3] ? gk : s_wmin[3];
  const int qmin = (int)(gk >> 13) - 32768;
  const int winner = (int)(gk & 8191u);
  const int thr = qmin + MARGIN_Q;
#pragma unroll
  for (int c = 0; c < 4; ++c) {
#pragma unroll
    for (int j = 0; j < 8; ++j) {
      if ((int)v[c][j] <= thr) {
        const int pos = atomicAdd(&s_cnt, 1);
        if (pos < MAXCAND) s_list[pos] = (c * 256 + t) * 8 + j;
      }
    }
  }
  __syncthreads();
  const int cnt = (s_cnt < MAXCAND) ? s_cnt : MAXCAND;
  if (t == 0) {
    gcount[row] = (cnt <= 1) ? 1 : cnt;
    out[OFF_IDX + row] = (float)winner;
    idxfinal[row] = winner;
    if (cnt <= 1) {
      const int p = prev[row];
      const float bias = 0.8f / (1.0f + expf(-adj[(size_t)p * NDIM + winner]));
      minfinal[row] = znorm[row] + (float)qmin * (1.0f / QSCALE) - bias;
    } else {
      minfinal[row] = znorm[row] + (float)qmin * (1.0f / QSCALE);  // refine overwrites
    }
  }
  if (cnt > 1 && t < cnt) gcand[(size_t)row * MAXCAND + t] = s_list[t];
}

// ============ exact fp32 refine of ambiguous rows (biased lex-min over candidates) ============
__global__ __launch_bounds__(64)
void refine_kernel(const float* __restrict__ gw_real, const float* __restrict__ gw_imag,
                   const float* __restrict__ codebook, const int* __restrict__ prev,
                   const float* __restrict__ adj, const float* __restrict__ znorm,
                   const float* __restrict__ cnorm,
                   const int* __restrict__ gcount, const int* __restrict__ gcand,
                   float* __restrict__ out, float* __restrict__ minfinal,
                   int* __restrict__ idxfinal) {
  const int row = blockIdx.x;
  const int t = threadIdx.x;   // 64 lanes, 16 contiguous floats each
  const int K = gcount[row];
  if (K <= 1) return;
  const int base = t * 16;
  const float* zp = (base < LDIM) ? gw_real + (size_t)row * LDIM + base
                                  : gw_imag + (size_t)row * LDIM + (base - LDIM);
  float z[16];
#pragma unroll
  for (int c = 0; c < 4; ++c) {
    const float4 v = reinterpret_cast<const float4*>(zp)[c];
    z[c*4+0] = v.x; z[c*4+1] = v.y; z[c*4+2] = v.z; z[c*4+3] = v.w;
  }
  const float zn = znorm[row];
  const int p = prev[row];
  float bestd = FLT_BIG;
  int besti = 0x7fffffff;
  for (int j = 0; j < K; ++j) {
    const int idx = gcand[(size_t)row * MAXCAND + j];
    const float* cp = codebook + (size_t)idx * DDIM + base;
    float dot = 0.f;
#pragma unroll
    for (int c = 0; c < 4; ++c) {
      const float4 v = reinterpret_cast<const float4*>(cp)[c];
      dot += z[c*4+0]*v.x + z[c*4+1]*v.y + z[c*4+2]*v.z + z[c*4+3]*v.w;
    }
    for (int m = 1; m < 64; m <<= 1) dot += __shfl_xor(dot, m, 64);
    const float d = zn + cnorm[idx] - 2.0f * dot
                  - 0.8f / (1.0f + expf(-adj[(size_t)p * NDIM + idx]));
    if (d < bestd || (d == bestd && idx < besti)) { bestd = d; besti = idx; }
  }
  if (t == 0) {
    out[OFF_IDX + row] = (float)besti;
    minfinal[row] = bestd;
    idxfinal[row] = besti;
  }
}

// ============ SHARED EPILOGUE ============

__global__ __launch_bounds__(256)
void epilogue_kernel(const float* __restrict__ gw_real, const float* __restrict__ gw_imag,
                     const float* __restrict__ codebook,
                     const float* __restrict__ sal_w, const float* __restrict__ sal_b,
                     const float* __restrict__ conf_w, const float* __restrict__ conf_b,
                     const float* __restrict__ minfinal, const int* __restrict__ idxfinal,
                     float* __restrict__ out, float* __restrict__ rowloss) {
  const int row = blockIdx.x;
  const int t = threadIdx.x;
  const int k = t << 2;
  const int idx = idxfinal[row];
  const float4 qv = *reinterpret_cast<const float4*>(codebook + (size_t)idx * DDIM + k);
  float4 z;
  if (k < LDIM) z = *reinterpret_cast<const float4*>(gw_real + (size_t)row * LDIM + k);
  else          z = *reinterpret_cast<const float4*>(gw_imag + (size_t)row * LDIM + (k - LDIM));
  const float dx = qv.x - z.x, dy = qv.y - z.y, dz = qv.z - z.z, dw = qv.w - z.w;
  float4 st;
  st.x = z.x + dx; st.y = z.y + dy; st.z = z.z + dz; st.w = z.w + dw;
  float* dst = (k < LDIM) ? (out + OFF_REAL + (size_t)row * LDIM + k)
                          : (out + OFF_IMAG + (size_t)row * LDIM + (k - LDIM));
  *reinterpret_cast<float4*>(dst) = st;
  const float4 sw = *reinterpret_cast<const float4*>(sal_w + k);
  const float4 cw = *reinterpret_cast<const float4*>(conf_w + k);
  const float sdot = st.x*sw.x + st.y*sw.y + st.z*sw.z + st.w*sw.w;
  const float cdot = st.x*cw.x + st.y*cw.y + st.z*cw.z + st.w*cw.w;
  const float dif = dx*dx + dy*dy + dz*dz + dw*dw;
  __shared__ float r1[256], r2[256], r3[256];
  r1[t] = sdot; r2[t] = cdot; r3[t] = dif;
  __syncthreads();
  for (int s = 128; s > 0; s >>= 1) {
    if (t < s) { r1[t] += r1[t + s]; r2[t] += r2[t + s]; r3[t] += r3[t + s]; }
    __syncthreads();
  }
  if (t == 0) {
    out[OFF_SAL + row]  = r1[0] + sal_b[0] + 0.1f * (-minfinal[row]);
    out[OFF_CONF + row] = 1.0f / (1.0f + expf(-(r2[0] + conf_b[0])));
    rowloss[row] = r3[0];
  }
}

__global__ __launch_bounds__(256)
void loss_kernel(const float* __restrict__ rowloss, float* __restrict__ out) {
  const int t = threadIdx.x;
  float s = 0.f;
  for (int i = t; i < RDIM; i += 256) s += rowloss[i];
  __shared__ float red[256];
  red[t] = s;
  __syncthreads();
  for (int st = 128; st > 0; st >>= 1) {
    if (t < st) red[t] += red[t + st];
    __syncthreads();
  }
  if (t == 0) {
    const float m = red[0] / (float)((size_t)RDIM * DDIM);
    out[OFF_LOSS] = m + 0.01f * m;
  }
}

// ============ FALLBACK (round-1 fp32 path) ============

__global__ __launch_bounds__(256)
void norms_kernel(const float* __restrict__ gw_real, const float* __restrict__ gw_imag,
                  const float* __restrict__ codebook,
                  float* __restrict__ znorm, float* __restrict__ cnorm) {
  const int id = blockIdx.x;
  const int t = threadIdx.x;
  float s;
  if (id < RDIM) {
    const float4* zr = reinterpret_cast<const float4*>(gw_real + (size_t)id * LDIM);
    const float4* zi = reinterpret_cast<const float4*>(gw_imag + (size_t)id * LDIM);
    const float4 v = (t < 128) ? zr[t] : zi[t - 128];
    s = v.x*v.x + v.y*v.y + v.z*v.z + v.w*v.w;
  } else {
    const float4* c = reinterpret_cast<const float4*>(codebook + (size_t)(id - RDIM) * DDIM);
    const float4 v = c[t];
    s = v.x*v.x + v.y*v.y + v.z*v.z + v.w*v.w;
  }
  __shared__ float red[256];
  red[t] = s;
  __syncthreads();
  for (int st = 128; st > 0; st >>= 1) {
    if (t < st) red[t] += red[t + st];
    __syncthreads();
  }
  if (t == 0) {
    if (id < RDIM) znorm[id] = red[0];
    else           cnorm[id - RDIM] = red[0];
  }
}

__global__ __launch_bounds__(256)
void dist_kernel(const float* __restrict__ gw_real, const float* __restrict__ gw_imag,
                 const float* __restrict__ codebook, const int* __restrict__ prev,
                 const float* __restrict__ adj, const float* __restrict__ znorm,
                 const float* __restrict__ cnorm,
                 float* __restrict__ ws_min, int* __restrict__ ws_idx) {
  __shared__ float As[16][64];
  __shared__ float Bs[16][64];
  __shared__ int prevs[64];
  const int bm = blockIdx.x, bn = blockIdx.y;
  const int row0 = bm * 64, col0 = bn * 64;
  const int tid = threadIdx.x;
  const int tx = tid & 15, ty = tid >> 4;
  if (tid < 64) prevs[tid] = prev[row0 + tid];
  const int lm = tid >> 2;
  const int lk = (tid & 3) << 2;
  const int arow = row0 + lm;
  const int brow = col0 + lm;
  float acc[4][4] = {{0.f,0.f,0.f,0.f},{0.f,0.f,0.f,0.f},{0.f,0.f,0.f,0.f},{0.f,0.f,0.f,0.f}};
  for (int kk = 0; kk < DDIM; kk += 16) {
    const int k = kk + lk;
    float4 a, b;
    if (k < LDIM) a = *reinterpret_cast<const float4*>(gw_real + (size_t)arow * LDIM + k);
    else          a = *reinterpret_cast<const float4*>(gw_imag + (size_t)arow * LDIM + (k - LDIM));
    b = *reinterpret_cast<const float4*>(codebook + (size_t)brow * DDIM + k);
    __syncthreads();
    As[lk+0][lm]=a.x; As[lk+1][lm]=a.y; As[lk+2][lm]=a.z; As[lk+3][lm]=a.w;
    Bs[lk+0][lm]=b.x; Bs[lk+1][lm]=b.y; Bs[lk+2][lm]=b.z; Bs[lk+3][lm]=b.w;
    __syncthreads();
#pragma unroll
    for (int k2 = 0; k2 < 16; ++k2) {
      const float4 a4 = *reinterpret_cast<const float4*>(&As[k2][ty << 2]);
      const float4 b4 = *reinterpret_cast<const float4*>(&Bs[k2][tx << 2]);
      const float av[4] = {a4.x, a4.y, a4.z, a4.w};
      const float bv[4] = {b4.x, b4.y, b4.z, b4.w};
#pragma unroll
      for (int i = 0; i < 4; ++i)
#pragma unroll
        for (int j = 0; j < 4; ++j)
          acc[i][j] = fmaf(av[i], bv[j], acc[i][j]);
    }
  }
  const float4 cn4 = *reinterpret_cast<const float4*>(cnorm + col0 + (tx << 2));
  const float cnv[4] = {cn4.x, cn4.y, cn4.z, cn4.w};
#pragma unroll
  for (int i = 0; i < 4; ++i) {
    const int rsub = (ty << 2) + i;
    const int row = row0 + rsub;
    const float zn = znorm[row];
    const int p = prevs[rsub];
    const float4 ad4 = *reinterpret_cast<const float4*>(adj + (size_t)p * NDIM + col0 + (tx << 2));
    const float adv[4] = {ad4.x, ad4.y, ad4.z, ad4.w};
    float bv = FLT_BIG;
    int bi = -1;
#pragma unroll
    for (int j = 0; j < 4; ++j) {
      const float bias = 0.8f * (1.0f / (1.0f + expf(-adv[j])));
      const float dv = (zn + cnv[j]) - 2.0f * acc[i][j] - bias;
      const int col = col0 + (tx << 2) + j;
      if (dv < bv) { bv = dv; bi = col; }
    }
    for (int m = 1; m < 16; m <<= 1) {
      const float ov = __shfl_xor(bv, m, 64);
      const int   oi = __shfl_xor(bi, m, 64);
      if (ov < bv || (ov == bv && oi < bi)) { bv = ov; bi = oi; }
    }
    if (tx == 0) {
      ws_min[(size_t)row * 128 + bn] = bv;
      ws_idx[(size_t)row * 128 + bn] = bi;
    }
  }
}

__global__ __launch_bounds__(128)
void argmin_reduce(const float* __restrict__ ws_min, const int* __restrict__ ws_idx,
                   float* __restrict__ out, float* __restrict__ minfinal,
                   int* __restrict__ idxfinal) {
  const int row = blockIdx.x;
  const int t = threadIdx.x;
  __shared__ float sv[128];
  __shared__ int   si[128];
  sv[t] = ws_min[(size_t)row * 128 + t];
  si[t] = ws_idx[(size_t)row * 128 + t];
  __syncthreads();
  for (int s = 64; s > 0; s >>= 1) {
    if (t < s) {
      const float ov = sv[t + s];
      const int   oi = si[t + s];
      if (ov < sv[t] || (ov == sv[t] && oi < si[t])) { sv[t] = ov; si[t] = oi; }
    }
    __syncthreads();
  }
  if (t == 0) {
    out[OFF_IDX + row] = (float)si[0];
    minfinal[row] = sv[0];
    idxfinal[row] = si[0];
  }
}

// ============ HOST ============

extern "C" void kernel_launch(void* const* d_in, const int* in_sizes, int n_in,
                              void* d_out, int out_size, void* d_ws, size_t ws_size,
                              hipStream_t stream) {
  const float* gw_real  = (const float*)d_in[0];
  const float* gw_imag  = (const float*)d_in[1];
  const int*   prev     = (const int*)d_in[2];
  const float* codebook = (const float*)d_in[3];
  const float* adj      = (const float*)d_in[4];
  const float* sal_w    = (const float*)d_in[5];
  const float* sal_b    = (const float*)d_in[6];
  const float* conf_w   = (const float*)d_in[7];
  const float* conf_b   = (const float*)d_in[8];
  float* out = (float*)d_out;
  char* ws = (char*)d_ws;

  const size_t matsz = (size_t)RDIM * DDIM;              // bf16 elements per matrix
  const size_t qsz   = (size_t)RDIM * NDIM;              // int16 score matrix
  size_t need = 2 * matsz * 2                            // zh, ch (bf16)
              + qsz * 2                                  // q (int16)
              + (size_t)RDIM * MAXCAND * 4               // gcand
              + 6 * (size_t)RDIM * 4 + 4096;             // gcount,znorm,cnorm,minfinal,idxfinal,rowloss

  if (ws_size >= need) {
    unsigned short* zh = (unsigned short*)ws;
    unsigned short* chh = zh + matsz;
    short* q = (short*)(chh + matsz);
    int*   gcand  = (int*)(q + qsz);
    int*   gcount = gcand + (size_t)RDIM * MAXCAND;
    float* znorm    = (float*)(gcount + RDIM);
    float* cnorm    = znorm + RDIM;
    float* minfinal = cnorm + NDIM;
    int*   idxfinal = (int*)(minfinal + RDIM);
    float* rowloss  = (float*)(idxfinal + RDIM);

    split_norms_kernel<<<RDIM + NDIM, 256, 0, stream>>>(gw_real, gw_imag, codebook,
                                                        zh, chh, znorm, cnorm);
    dist_mfma_kernel<<<1024, 512, 0, stream>>>(zh, chh, cnorm, q);
    collect_kernel<<<RDIM, 256, 0, stream>>>(q, prev, adj, znorm,
                                             out, minfinal, idxfinal, gcount, gcand);
    refine_kernel<<<RDIM, 64, 0, stream>>>(gw_real, gw_imag, codebook, prev, adj,
                                           znorm, cnorm, gcount, gcand,
                                           out, minfinal, idxfinal);
    epilogue_kernel<<<RDIM, 256, 0, stream>>>(gw_real, gw_imag, codebook, sal_w, sal_b,
                                              conf_w, conf_b, minfinal, idxfinal, out, rowloss);
    loss_kernel<<<1, 256, 0, stream>>>(rowloss, out);
  } else {
    float* ws_min   = (float*)ws;
    int*   ws_idx   = (int*)(ws + (size_t)RDIM * 128 * 4);
    float* znorm    = (float*)(ws + (size_t)RDIM * 128 * 8);
    float* cnorm    = znorm + RDIM;
    float* minfinal = cnorm + NDIM;
    int*   idxfinal = (int*)(minfinal + RDIM);
    float* rowloss  = (float*)(idxfinal + RDIM);

    norms_kernel<<<RDIM + NDIM, 256, 0, stream>>>(gw_real, gw_imag, codebook, znorm, cnorm);
    dist_kernel<<<dim3(RDIM / 64, NDIM / 64), 256, 0, stream>>>(
        gw_real, gw_imag, codebook, prev, adj, znorm, cnorm, ws_min, ws_idx);
    argmin_reduce<<<RDIM, 128, 0, stream>>>(ws_min, ws_idx, out, minfinal, idxfinal);
    epilogue_kernel<<<RDIM, 256, 0, stream>>>(gw_real, gw_imag, codebook, sal_w, sal_b,
                                              conf_w, conf_b, minfinal, idxfinal, out, rowloss);
    loss_kernel<<<1, 256, 0, stream>>>(rowloss, out);
  }
}